// Round 2
// baseline (1803.850 us; speedup 1.0000x reference)
//
#include <hip/hip_runtime.h>

#define B_ 4
#define T_ 1024
#define HID_ 1024
#define H_ 8
#define CONV_DIM_ 3072
#define MROWS (B_*T_)

// C[M,N] = A[M,K](fp32,row-major) * W[N,K]^T (fp32,row-major), fp32 out.
__global__ __launch_bounds__(256) void gemm_bt_kernel(
    const float* __restrict__ A, const float* __restrict__ W, float* __restrict__ C,
    int M, int N, int K) {
  __shared__ float As[64][33];
  __shared__ float Ws[64][33];
  const int tid = threadIdx.x;
  const int bm = blockIdx.y * 64;
  const int bn = blockIdx.x * 64;
  const int tx = tid & 15;
  const int ty = tid >> 4;
  const int lr = tid >> 2;          // 0..63 row of tile
  const int lk = (tid & 3) * 8;     // 0,8,16,24 (k offset within 32)
  float acc[4][4];
  #pragma unroll
  for (int i=0;i<4;++i)
    #pragma unroll
    for (int j=0;j<4;++j) acc[i][j]=0.f;

  for (int k0 = 0; k0 < K; k0 += 32) {
    float4 a0 = *(const float4*)(A + (size_t)(bm+lr)*K + k0 + lk);
    float4 a1 = *(const float4*)(A + (size_t)(bm+lr)*K + k0 + lk + 4);
    float4 w0 = *(const float4*)(W + (size_t)(bn+lr)*K + k0 + lk);
    float4 w1 = *(const float4*)(W + (size_t)(bn+lr)*K + k0 + lk + 4);
    As[lr][lk+0]=a0.x; As[lr][lk+1]=a0.y; As[lr][lk+2]=a0.z; As[lr][lk+3]=a0.w;
    As[lr][lk+4]=a1.x; As[lr][lk+5]=a1.y; As[lr][lk+6]=a1.z; As[lr][lk+7]=a1.w;
    Ws[lr][lk+0]=w0.x; Ws[lr][lk+1]=w0.y; Ws[lr][lk+2]=w0.z; Ws[lr][lk+3]=w0.w;
    Ws[lr][lk+4]=w1.x; Ws[lr][lk+5]=w1.y; Ws[lr][lk+6]=w1.z; Ws[lr][lk+7]=w1.w;
    __syncthreads();
    #pragma unroll
    for (int kk=0; kk<32; ++kk){
      float a[4], b[4];
      #pragma unroll
      for (int i=0;i<4;++i) a[i] = As[ty*4+i][kk];
      #pragma unroll
      for (int j=0;j<4;++j) b[j] = Ws[tx*4+j][kk];
      #pragma unroll
      for (int i=0;i<4;++i)
        #pragma unroll
        for (int j=0;j<4;++j)
          acc[i][j] = fmaf(a[i], b[j], acc[i][j]);
    }
    __syncthreads();
  }
  #pragma unroll
  for (int i=0;i<4;++i){
    size_t row = (size_t)(bm + ty*4 + i);
    #pragma unroll
    for (int j=0;j<4;++j)
      C[row*N + bn + tx*4 + j] = acc[i][j];
  }
}

// bb/aa projections (N=8 each) fused with beta/alpha computation. [B,H,T] outputs.
__global__ __launch_bounds__(128) void proj_ba_kernel(
    const float* __restrict__ hs, const float* __restrict__ b_w, const float* __restrict__ a_w,
    const float* __restrict__ dt_bias, const float* __restrict__ A_log,
    float* __restrict__ alpha, float* __restrict__ beta) {
  const int bt = blockIdx.x;
  const int b = bt >> 10;
  const int t = bt & 1023;
  const int tid = threadIdx.x;
  const int grp = tid >> 3;   // 0..15: 0-7 -> bb[h], 8-15 -> aa[h]
  const int l8 = tid & 7;
  const int h = grp & 7;
  const bool isA = grp >= 8;
  const float* w = (isA ? a_w : b_w) + (size_t)h * HID_;
  const float* x = hs + (size_t)bt * HID_;
  float s = 0.f;
  for (int e = l8*4; e < HID_; e += 32){
    float4 xv = *(const float4*)(x + e);
    float4 wv = *(const float4*)(w + e);
    s = fmaf(xv.x, wv.x, s);
    s = fmaf(xv.y, wv.y, s);
    s = fmaf(xv.z, wv.z, s);
    s = fmaf(xv.w, wv.w, s);
  }
  s += __shfl_xor(s,1); s += __shfl_xor(s,2); s += __shfl_xor(s,4);
  if (l8 == 0) {
    size_t o = ((size_t)(b*H_ + h))*T_ + t;
    if (!isA) {
      beta[o] = 1.f/(1.f+expf(-s));
    } else {
      float xx = s + dt_bias[h];
      float sp = fmaxf(xx,0.f) + log1pf(expf(-fabsf(xx)));   // softplus
      alpha[o] = expf(-expf(A_log[h]) * sp);
    }
  }
}

// causal depthwise conv (K=4) + scatter to q/k/v in [B,H,T,128] fp32
__global__ __launch_bounds__(256) void conv_route_kernel(
    const float* __restrict__ mixed, const float* __restrict__ conv_w,
    float* __restrict__ qb, float* __restrict__ kb, float* __restrict__ vb) {
  const int idx = blockIdx.x*256 + threadIdx.x;
  const int c = idx % CONV_DIM_;
  const int bt = idx / CONV_DIM_;
  const int t = bt & 1023;
  const int b = bt >> 10;
  float w[4];
  #pragma unroll
  for (int j=0;j<4;++j) w[j] = conv_w[c*4+j];
  float s = 0.f;
  #pragma unroll
  for (int j=0;j<4;++j){
    int tt = t - 3 + j;
    if (tt >= 0) s = fmaf(w[j], mixed[((size_t)(b*T_+tt))*CONV_DIM_ + c], s);
  }
  const int part = c >> 10;
  const int cc = c & 1023;
  const int hh = cc >> 7;
  const int d = cc & 127;
  float* dst = part==0 ? qb : (part==1 ? kb : vb);
  dst[(((size_t)(b*H_+hh))*T_ + t)*128 + d] = s;
}

// gated delta recurrence. 256 blocks = 32 (b,h) x 8 dv-slices; 64 threads:
// 16 columns x 4 row-quarters; 32 fp32 state regs/thread; shfl reductions.
__global__ __launch_bounds__(64) void scan_kernel(
    const float* __restrict__ qb, const float* __restrict__ kb, const float* __restrict__ vb,
    const float* __restrict__ alpha, const float* __restrict__ beta,
    float* __restrict__ ob) {
  const int bh = blockIdx.x >> 3;
  const int slice = blockIdx.x & 7;
  const int tid = threadIdx.x;
  const int col = tid >> 2;
  const int quarter = tid & 3;
  const int dv = slice*16 + col;
  const float* qp = qb + (size_t)bh*T_*128;
  const float* kp = kb + (size_t)bh*T_*128;
  const float* vp = vb + (size_t)bh*T_*128;
  const float* ap = alpha + (size_t)bh*T_;
  const float* bp = beta  + (size_t)bh*T_;
  float* op = ob + (size_t)bh*T_*128;

  float S[32];
  #pragma unroll
  for (int i=0;i<32;++i) S[i]=0.f;

  float4 kA[8], qA[8], kB[8], qB[8];
  float vA, aA, bA2, vB, aB, bB2;

  auto load_t = [&](int t, float4* k4, float4* q4, float& v, float& al, float& be){
    const float4* kk = (const float4*)(kp + (size_t)t*128 + quarter*32);
    const float4* qq = (const float4*)(qp + (size_t)t*128 + quarter*32);
    #pragma unroll
    for (int i=0;i<8;++i){ k4[i]=kk[i]; q4[i]=qq[i]; }
    v = vp[(size_t)t*128 + dv];
    al = ap[t]; be = bp[t];
  };

  auto step = [&](int t, const float4* k4, const float4* q4, float v, float al, float be){
    float s0=0,s1=0,s2=0,s3=0;
    #pragma unroll
    for (int i=0;i<8;++i){
      s0 = fmaf(k4[i].x, S[4*i+0], s0);
      s1 = fmaf(k4[i].y, S[4*i+1], s1);
      s2 = fmaf(k4[i].z, S[4*i+2], s2);
      s3 = fmaf(k4[i].w, S[4*i+3], s3);
    }
    float kvp = (s0+s1)+(s2+s3);
    kvp += __shfl_xor(kvp, 1);
    kvp += __shfl_xor(kvp, 2);
    float delta = (v - al*kvp) * be;   // k·(alpha*S_old) = alpha*(k·S_old)
    float o0=0,o1=0,o2=0,o3=0;
    #pragma unroll
    for (int i=0;i<8;++i){
      S[4*i+0] = fmaf(k4[i].x, delta, al*S[4*i+0]); o0 = fmaf(q4[i].x, S[4*i+0], o0);
      S[4*i+1] = fmaf(k4[i].y, delta, al*S[4*i+1]); o1 = fmaf(q4[i].y, S[4*i+1], o1);
      S[4*i+2] = fmaf(k4[i].z, delta, al*S[4*i+2]); o2 = fmaf(q4[i].z, S[4*i+2], o2);
      S[4*i+3] = fmaf(k4[i].w, delta, al*S[4*i+3]); o3 = fmaf(q4[i].w, S[4*i+3], o3);
    }
    float o = (o0+o1)+(o2+o3);
    o += __shfl_xor(o,1);
    o += __shfl_xor(o,2);
    if (quarter==0) op[(size_t)t*128 + dv] = o;
  };

  load_t(0, kA, qA, vA, aA, bA2);
  for (int t=0; t<T_; t+=2){
    load_t(t+1, kB, qB, vB, aB, bB2);
    step(t, kA, qA, vA, aA, bA2);
    if (t+2 < T_) load_t(t+2, kA, qA, vA, aA, bA2);
    step(t+1, kB, qB, vB, aB, bB2);
  }
}

// rmsnorm(o)*norm_w*silu(z) -> fp32 [B,T,1024] (H-interleaved layout)
__global__ __launch_bounds__(64) void gnorm_kernel(
    const float* __restrict__ ob, const float* __restrict__ zb,
    const float* __restrict__ norm_w, float* __restrict__ og) {
  const int idx = blockIdx.x;        // bh*T + t
  const int t = idx & 1023;
  const int bh = idx >> 10;
  const int b = bh >> 3;
  const int h = bh & 7;
  const int tid = threadIdx.x;
  const float* o = ob + ((size_t)bh*T_ + t)*128;
  float2 ov = *(const float2*)(o + tid*2);
  float ss = fmaf(ov.x, ov.x, ov.y*ov.y);
  #pragma unroll
  for (int m=1; m<64; m<<=1) ss += __shfl_xor(ss, m);
  float inv = rsqrtf(ss*(1.f/128.f) + 1e-6f);
  size_t zoff = ((size_t)(b*T_+t))*1024 + (size_t)h*128 + tid*2;
  float z0 = zb[zoff], z1 = zb[zoff+1];
  float n0 = norm_w[tid*2], n1 = norm_w[tid*2+1];
  float r0 = ov.x*inv*n0 * z0/(1.f+expf(-z0));
  float r1 = ov.y*inv*n1 * z1/(1.f+expf(-z1));
  og[zoff]   = r0;
  og[zoff+1] = r1;
}

extern "C" void kernel_launch(void* const* d_in, const int* in_sizes, int n_in,
                              void* d_out, int out_size, void* d_ws, size_t ws_size,
                              hipStream_t stream) {
  const float* hs     = (const float*)d_in[0];
  const float* qkv_w  = (const float*)d_in[1];
  const float* z_w    = (const float*)d_in[2];
  const float* b_w    = (const float*)d_in[3];
  const float* a_w    = (const float*)d_in[4];
  const float* conv_w = (const float*)d_in[5];
  const float* dt_bias= (const float*)d_in[6];
  const float* A_log  = (const float*)d_in[7];
  const float* norm_w = (const float*)d_in[8];
  const float* out_w  = (const float*)d_in[9];
  float* out = (float*)d_out;

  char* wsp = (char*)d_ws;
  size_t off = 0;
  auto give = [&](size_t bytes)->char*{
    char* p = wsp + off; off += (bytes + 255) & ~(size_t)255; return p;
  };
  float* mixed = (float*)give((size_t)MROWS*CONV_DIM_*4);  // 48 MB
  float* zbuf  = (float*)give((size_t)MROWS*1024*4);       // 16 MB
  float* qb    = (float*)give((size_t)32*T_*128*4);
  float* kb    = (float*)give((size_t)32*T_*128*4);
  float* vb    = (float*)give((size_t)32*T_*128*4);
  float* alpha = (float*)give((size_t)32*T_*4);
  float* beta  = (float*)give((size_t)32*T_*4);
  // mixed is dead after conv_route; reuse its space for ob and og.
  float* ob    = mixed;                                    // 16 MB (fits in 48)
  float* og    = mixed + (size_t)4*1024*1024;              // next 16 MB

  gemm_bt_kernel<<<dim3(CONV_DIM_/64, MROWS/64), dim3(256), 0, stream>>>(hs, qkv_w, mixed, MROWS, CONV_DIM_, HID_);
  gemm_bt_kernel<<<dim3(1024/64, MROWS/64), dim3(256), 0, stream>>>(hs, z_w, zbuf, MROWS, 1024, HID_);
  proj_ba_kernel<<<dim3(MROWS), dim3(128), 0, stream>>>(hs, b_w, a_w, dt_bias, A_log, alpha, beta);
  conv_route_kernel<<<dim3((MROWS*CONV_DIM_)/256), dim3(256), 0, stream>>>(mixed, conv_w, qb, kb, vb);
  scan_kernel<<<dim3(256), dim3(64), 0, stream>>>(qb, kb, vb, alpha, beta, ob);
  gnorm_kernel<<<dim3(32*T_), dim3(64), 0, stream>>>(ob, zbuf, norm_w, og);
  gemm_bt_kernel<<<dim3(1024/64, MROWS/64), dim3(256), 0, stream>>>(og, out_w, out, MROWS, 1024, HID_);
}

// Round 3
// 1339.064 us; speedup vs baseline: 1.3471x; 1.3471x over previous
//
#include <hip/hip_runtime.h>

#define B_ 4
#define T_ 1024
#define HID_ 1024
#define H_ 8
#define CONV_DIM_ 3072
#define MROWS (B_*T_)

// C[M,N] = A[M,K](fp32,row-major) * W[N,K]^T (fp32,row-major), fp32 out.
__global__ __launch_bounds__(256) void gemm_bt_kernel(
    const float* __restrict__ A, const float* __restrict__ W, float* __restrict__ C,
    int M, int N, int K) {
  __shared__ float As[64][33];
  __shared__ float Ws[64][33];
  const int tid = threadIdx.x;
  const int bm = blockIdx.y * 64;
  const int bn = blockIdx.x * 64;
  const int tx = tid & 15;
  const int ty = tid >> 4;
  const int lr = tid >> 2;          // 0..63 row of tile
  const int lk = (tid & 3) * 8;     // 0,8,16,24 (k offset within 32)
  float acc[4][4];
  #pragma unroll
  for (int i=0;i<4;++i)
    #pragma unroll
    for (int j=0;j<4;++j) acc[i][j]=0.f;

  for (int k0 = 0; k0 < K; k0 += 32) {
    float4 a0 = *(const float4*)(A + (size_t)(bm+lr)*K + k0 + lk);
    float4 a1 = *(const float4*)(A + (size_t)(bm+lr)*K + k0 + lk + 4);
    float4 w0 = *(const float4*)(W + (size_t)(bn+lr)*K + k0 + lk);
    float4 w1 = *(const float4*)(W + (size_t)(bn+lr)*K + k0 + lk + 4);
    As[lr][lk+0]=a0.x; As[lr][lk+1]=a0.y; As[lr][lk+2]=a0.z; As[lr][lk+3]=a0.w;
    As[lr][lk+4]=a1.x; As[lr][lk+5]=a1.y; As[lr][lk+6]=a1.z; As[lr][lk+7]=a1.w;
    Ws[lr][lk+0]=w0.x; Ws[lr][lk+1]=w0.y; Ws[lr][lk+2]=w0.z; Ws[lr][lk+3]=w0.w;
    Ws[lr][lk+4]=w1.x; Ws[lr][lk+5]=w1.y; Ws[lr][lk+6]=w1.z; Ws[lr][lk+7]=w1.w;
    __syncthreads();
    #pragma unroll
    for (int kk=0; kk<32; ++kk){
      float a[4], b[4];
      #pragma unroll
      for (int i=0;i<4;++i) a[i] = As[ty*4+i][kk];
      #pragma unroll
      for (int j=0;j<4;++j) b[j] = Ws[tx*4+j][kk];
      #pragma unroll
      for (int i=0;i<4;++i)
        #pragma unroll
        for (int j=0;j<4;++j)
          acc[i][j] = fmaf(a[i], b[j], acc[i][j]);
    }
    __syncthreads();
  }
  #pragma unroll
  for (int i=0;i<4;++i){
    size_t row = (size_t)(bm + ty*4 + i);
    #pragma unroll
    for (int j=0;j<4;++j)
      C[row*N + bn + tx*4 + j] = acc[i][j];
  }
}

// bb/aa projections (N=8 each) fused with beta / g=log(alpha) computation. [B,H,T] outputs.
__global__ __launch_bounds__(128) void proj_ba_kernel(
    const float* __restrict__ hs, const float* __restrict__ b_w, const float* __restrict__ a_w,
    const float* __restrict__ dt_bias, const float* __restrict__ A_log,
    float* __restrict__ gout, float* __restrict__ beta) {
  const int bt = blockIdx.x;
  const int b = bt >> 10;
  const int t = bt & 1023;
  const int tid = threadIdx.x;
  const int grp = tid >> 3;   // 0..15: 0-7 -> bb[h], 8-15 -> aa[h]
  const int l8 = tid & 7;
  const int h = grp & 7;
  const bool isA = grp >= 8;
  const float* w = (isA ? a_w : b_w) + (size_t)h * HID_;
  const float* x = hs + (size_t)bt * HID_;
  float s = 0.f;
  for (int e = l8*4; e < HID_; e += 32){
    float4 xv = *(const float4*)(x + e);
    float4 wv = *(const float4*)(w + e);
    s = fmaf(xv.x, wv.x, s);
    s = fmaf(xv.y, wv.y, s);
    s = fmaf(xv.z, wv.z, s);
    s = fmaf(xv.w, wv.w, s);
  }
  s += __shfl_xor(s,1); s += __shfl_xor(s,2); s += __shfl_xor(s,4);
  if (l8 == 0) {
    size_t o = ((size_t)(b*H_ + h))*T_ + t;
    if (!isA) {
      beta[o] = 1.f/(1.f+expf(-s));
    } else {
      float xx = s + dt_bias[h];
      float sp = fmaxf(xx,0.f) + log1pf(expf(-fabsf(xx)));   // softplus
      gout[o] = -expf(A_log[h]) * sp;                        // store g = log(alpha)
    }
  }
}

// causal depthwise conv (K=4) + scatter to q/k/v in [B,H,T,128] fp32
__global__ __launch_bounds__(256) void conv_route_kernel(
    const float* __restrict__ mixed, const float* __restrict__ conv_w,
    float* __restrict__ qb, float* __restrict__ kb, float* __restrict__ vb) {
  const int idx = blockIdx.x*256 + threadIdx.x;
  const int c = idx % CONV_DIM_;
  const int bt = idx / CONV_DIM_;
  const int t = bt & 1023;
  const int b = bt >> 10;
  float w[4];
  #pragma unroll
  for (int j=0;j<4;++j) w[j] = conv_w[c*4+j];
  float s = 0.f;
  #pragma unroll
  for (int j=0;j<4;++j){
    int tt = t - 3 + j;
    if (tt >= 0) s = fmaf(w[j], mixed[((size_t)(b*T_+tt))*CONV_DIM_ + c], s);
  }
  const int part = c >> 10;
  const int cc = c & 1023;
  const int hh = cc >> 7;
  const int d = cc & 127;
  float* dst = part==0 ? qb : (part==1 ? kb : vb);
  dst[(((size_t)(b*H_+hh))*T_ + t)*128 + d] = s;
}

// Chunked gated delta rule (WY form), C=64, fp32. Blocks: 32 bh x 8 dv-slices(16).
// Per chunk: A = strict-lower(beta_i exp(l_i-l_j) k_i.k_j); (I+A)W = bV - b*gamma*K S0;
// O = gamma*Q S0 + B W (B incl-lower exp(l_i-l_j) q_i.k_j); S0 = gC S0 + sum exp(lC-l_j) k_j w_j^T.
__global__ __launch_bounds__(256) void scan_chunk_kernel(
    const float* __restrict__ qb, const float* __restrict__ kb, const float* __restrict__ vb,
    const float* __restrict__ gbuf, const float* __restrict__ bbuf,
    float* __restrict__ ob) {
  const int bh = blockIdx.x >> 3;
  const int sl = blockIdx.x & 7;
  const int tid = threadIdx.x;

  __shared__ float sK[64][132];    // K chunk [row][dk]
  __shared__ float sA[64][68];     // A, later B
  __shared__ float sS0T[16][132];  // S0 transposed [dv-slice][dk]
  __shared__ float sW[64][17];     // RHS -> W
  __shared__ float lL[64];         // inclusive cumsum of log-alpha in chunk
  __shared__ float bL[64];         // beta in chunk

  const float* kg = kb + (size_t)bh*T_*128;
  const float* qg = qb + (size_t)bh*T_*128;
  const float* vg = vb + (size_t)bh*T_*128 + sl*16;
  const float* gg = gbuf + (size_t)bh*T_;
  const float* beg = bbuf + (size_t)bh*T_;
  float* og = ob + (size_t)bh*T_*128 + sl*16;

  // role decodes
  const int it = tid >> 4, jt = tid & 15;          // tile phases (A, B)
  const int ro = tid >> 2, dg = (tid & 3) * 4;     // row phases (RHS, BW, scale)
  const int wv = tid >> 6, ln = tid & 63;          // subst: wave-local
  const int dd = ln >> 4, rr = ln & 15;
  const int dsub = wv*4 + dd;                       // subst column (0..15)
  const int dk0 = (tid >> 4) * 8, dcol = tid & 15;  // S0-update

  for (int z = tid; z < 16*132; z += 256) ((float*)sS0T)[z] = 0.f;

  for (int ch = 0; ch < 16; ++ch) {
    const int t0 = ch * 64;
    __syncthreads();   // prev chunk fully done (S0 updated, sK free)

    // ---- load K chunk + per-chunk vectors
    #pragma unroll
    for (int i = 0; i < 8; ++i) {
      int f4 = tid + 256*i;
      int row = f4 >> 5, c = f4 & 31;
      float4 val = *(const float4*)(kg + (size_t)(t0+row)*128 + c*4);
      *(float4*)&sK[row][c*4] = val;
    }
    if (tid < 64) {
      float x = gg[t0 + tid];
      #pragma unroll
      for (int o = 1; o < 64; o <<= 1) {
        float y = __shfl_up(x, o);
        if (tid >= o) x += y;
      }
      lL[tid] = x;
      bL[tid] = beg[t0 + tid];
    }
    __syncthreads();

    // ---- phase A
    {
      float acc[4][4] = {};
      if (jt <= it) {
        for (int kk = 0; kk < 128; kk += 4) {
          float4 ka[4], kc[4];
          #pragma unroll
          for (int r = 0; r < 4; ++r) {
            ka[r] = *(const float4*)&sK[it*4+r][kk];
            kc[r] = *(const float4*)&sK[jt*4+r][kk];
          }
          #pragma unroll
          for (int a = 0; a < 4; ++a)
            #pragma unroll
            for (int b = 0; b < 4; ++b) {
              acc[a][b] = fmaf(ka[a].x, kc[b].x, acc[a][b]);
              acc[a][b] = fmaf(ka[a].y, kc[b].y, acc[a][b]);
              acc[a][b] = fmaf(ka[a].z, kc[b].z, acc[a][b]);
              acc[a][b] = fmaf(ka[a].w, kc[b].w, acc[a][b]);
            }
        }
      }
      #pragma unroll
      for (int a = 0; a < 4; ++a) {
        int i = it*4 + a;
        float bi = bL[i], li = lL[i];
        #pragma unroll
        for (int b = 0; b < 4; ++b) {
          int j = jt*4 + b;
          sA[i][j] = (j < i) ? bi * __expf(li - lL[j]) * acc[a][b] : 0.f;
        }
      }
    }
    __syncthreads();

    // ---- phase RHS: sW = beta*v - beta*gamma*(K S0)
    {
      float a0=0,a1=0,a2=0,a3=0;
      for (int kk = 0; kk < 128; kk += 4) {
        float4 kv = *(const float4*)&sK[ro][kk];
        float4 s0 = *(const float4*)&sS0T[dg+0][kk];
        float4 s1 = *(const float4*)&sS0T[dg+1][kk];
        float4 s2 = *(const float4*)&sS0T[dg+2][kk];
        float4 s3 = *(const float4*)&sS0T[dg+3][kk];
        a0 = fmaf(kv.x,s0.x,fmaf(kv.y,s0.y,fmaf(kv.z,s0.z,fmaf(kv.w,s0.w,a0))));
        a1 = fmaf(kv.x,s1.x,fmaf(kv.y,s1.y,fmaf(kv.z,s1.z,fmaf(kv.w,s1.w,a1))));
        a2 = fmaf(kv.x,s2.x,fmaf(kv.y,s2.y,fmaf(kv.z,s2.z,fmaf(kv.w,s2.w,a2))));
        a3 = fmaf(kv.x,s3.x,fmaf(kv.y,s3.y,fmaf(kv.z,s3.z,fmaf(kv.w,s3.w,a3))));
      }
      float be = bL[ro], ga = __expf(lL[ro]);
      float cg = be * ga;
      float4 vvv = *(const float4*)(vg + (size_t)(t0+ro)*128 + dg);
      sW[ro][dg+0] = be*vvv.x - cg*a0;
      sW[ro][dg+1] = be*vvv.y - cg*a1;
      sW[ro][dg+2] = be*vvv.z - cg*a2;
      sW[ro][dg+3] = be*vvv.w - cg*a3;
    }
    __syncthreads();

    // ---- phase subst: W = (I+A)^-1 RHS  (wave-local, column-partitioned)
    {
      float rh[4];
      #pragma unroll
      for (int m = 0; m < 4; ++m) rh[m] = sW[rr + 16*m][dsub];
      #pragma unroll
      for (int j = 0; j < 63; ++j) {
        int src = (dd << 4) | (j & 15);
        float wj = __shfl(rh[j >> 4], src);
        #pragma unroll
        for (int m = 0; m < 4; ++m)
          rh[m] = fmaf(-sA[rr + 16*m][j], wj, rh[m]);
      }
      #pragma unroll
      for (int m = 0; m < 4; ++m) sW[rr + 16*m][dsub] = rh[m];
    }
    __syncthreads();

    // ---- phase B: B = incl-lower( exp(l_i-l_j) q_i.k_j ) -> sA
    {
      float acc[4][4] = {};
      if (jt <= it) {
        for (int kk = 0; kk < 128; kk += 4) {
          float4 qa[4], kc[4];
          #pragma unroll
          for (int r = 0; r < 4; ++r) {
            qa[r] = *(const float4*)(qg + (size_t)(t0+it*4+r)*128 + kk);
            kc[r] = *(const float4*)&sK[jt*4+r][kk];
          }
          #pragma unroll
          for (int a = 0; a < 4; ++a)
            #pragma unroll
            for (int b = 0; b < 4; ++b) {
              acc[a][b] = fmaf(qa[a].x, kc[b].x, acc[a][b]);
              acc[a][b] = fmaf(qa[a].y, kc[b].y, acc[a][b]);
              acc[a][b] = fmaf(qa[a].z, kc[b].z, acc[a][b]);
              acc[a][b] = fmaf(qa[a].w, kc[b].w, acc[a][b]);
            }
        }
      }
      #pragma unroll
      for (int a = 0; a < 4; ++a) {
        int i = it*4 + a;
        float li = lL[i];
        #pragma unroll
        for (int b = 0; b < 4; ++b) {
          int j = jt*4 + b;
          sA[i][j] = (j <= i) ? __expf(li - lL[j]) * acc[a][b] : 0.f;
        }
      }
    }
    __syncthreads();

    // ---- phase O: O = gamma * (Q S0) + B W   -> global
    {
      float q0=0,q1=0,q2=0,q3=0;
      for (int kk = 0; kk < 128; kk += 4) {
        float4 qv = *(const float4*)(qg + (size_t)(t0+ro)*128 + kk);
        float4 s0 = *(const float4*)&sS0T[dg+0][kk];
        float4 s1 = *(const float4*)&sS0T[dg+1][kk];
        float4 s2 = *(const float4*)&sS0T[dg+2][kk];
        float4 s3 = *(const float4*)&sS0T[dg+3][kk];
        q0 = fmaf(qv.x,s0.x,fmaf(qv.y,s0.y,fmaf(qv.z,s0.z,fmaf(qv.w,s0.w,q0))));
        q1 = fmaf(qv.x,s1.x,fmaf(qv.y,s1.y,fmaf(qv.z,s1.z,fmaf(qv.w,s1.w,q1))));
        q2 = fmaf(qv.x,s2.x,fmaf(qv.y,s2.y,fmaf(qv.z,s2.z,fmaf(qv.w,s2.w,q2))));
        q3 = fmaf(qv.x,s3.x,fmaf(qv.y,s3.y,fmaf(qv.z,s3.z,fmaf(qv.w,s3.w,q3))));
      }
      float w0=0,w1=0,w2=0,w3=0;
      for (int j = 0; j < 64; j += 4) {
        float4 bv = *(const float4*)&sA[ro][j];
        w0 = fmaf(bv.x, sW[j+0][dg+0], w0); w1 = fmaf(bv.x, sW[j+0][dg+1], w1);
        w2 = fmaf(bv.x, sW[j+0][dg+2], w2); w3 = fmaf(bv.x, sW[j+0][dg+3], w3);
        w0 = fmaf(bv.y, sW[j+1][dg+0], w0); w1 = fmaf(bv.y, sW[j+1][dg+1], w1);
        w2 = fmaf(bv.y, sW[j+1][dg+2], w2); w3 = fmaf(bv.y, sW[j+1][dg+3], w3);
        w0 = fmaf(bv.z, sW[j+2][dg+0], w0); w1 = fmaf(bv.z, sW[j+2][dg+1], w1);
        w2 = fmaf(bv.z, sW[j+2][dg+2], w2); w3 = fmaf(bv.z, sW[j+2][dg+3], w3);
        w0 = fmaf(bv.w, sW[j+3][dg+0], w0); w1 = fmaf(bv.w, sW[j+3][dg+1], w1);
        w2 = fmaf(bv.w, sW[j+3][dg+2], w2); w3 = fmaf(bv.w, sW[j+3][dg+3], w3);
      }
      float ga = __expf(lL[ro]);
      float4 o;
      o.x = fmaf(ga, q0, w0);
      o.y = fmaf(ga, q1, w1);
      o.z = fmaf(ga, q2, w2);
      o.w = fmaf(ga, q3, w3);
      *(float4*)(og + (size_t)(t0+ro)*128 + dg) = o;
    }
    __syncthreads();

    // ---- scale W rows by exp(lC - l_j)
    {
      float sc = __expf(lL[63] - lL[ro]);
      sW[ro][dg+0] *= sc;
      sW[ro][dg+1] *= sc;
      sW[ro][dg+2] *= sc;
      sW[ro][dg+3] *= sc;
    }
    __syncthreads();

    // ---- S0 update: S0 = gC*S0 + K^T Wscaled
    {
      float gC = __expf(lL[63]);
      float4 sa = *(const float4*)&sS0T[dcol][dk0];
      float4 sb = *(const float4*)&sS0T[dcol][dk0+4];
      sa.x*=gC; sa.y*=gC; sa.z*=gC; sa.w*=gC;
      sb.x*=gC; sb.y*=gC; sb.z*=gC; sb.w*=gC;
      for (int j = 0; j < 64; ++j) {
        float wvv = sW[j][dcol];
        float4 k1 = *(const float4*)&sK[j][dk0];
        float4 k2 = *(const float4*)&sK[j][dk0+4];
        sa.x = fmaf(k1.x, wvv, sa.x); sa.y = fmaf(k1.y, wvv, sa.y);
        sa.z = fmaf(k1.z, wvv, sa.z); sa.w = fmaf(k1.w, wvv, sa.w);
        sb.x = fmaf(k2.x, wvv, sb.x); sb.y = fmaf(k2.y, wvv, sb.y);
        sb.z = fmaf(k2.z, wvv, sb.z); sb.w = fmaf(k2.w, wvv, sb.w);
      }
      *(float4*)&sS0T[dcol][dk0]   = sa;
      *(float4*)&sS0T[dcol][dk0+4] = sb;
    }
  }
}

// rmsnorm(o)*norm_w*silu(z) -> fp32 [B,T,1024] (H-interleaved layout)
__global__ __launch_bounds__(64) void gnorm_kernel(
    const float* __restrict__ ob, const float* __restrict__ zb,
    const float* __restrict__ norm_w, float* __restrict__ og) {
  const int idx = blockIdx.x;        // bh*T + t
  const int t = idx & 1023;
  const int bh = idx >> 10;
  const int b = bh >> 3;
  const int h = bh & 7;
  const int tid = threadIdx.x;
  const float* o = ob + ((size_t)bh*T_ + t)*128;
  float2 ov = *(const float2*)(o + tid*2);
  float ss = fmaf(ov.x, ov.x, ov.y*ov.y);
  #pragma unroll
  for (int m=1; m<64; m<<=1) ss += __shfl_xor(ss, m);
  float inv = rsqrtf(ss*(1.f/128.f) + 1e-6f);
  size_t zoff = ((size_t)(b*T_+t))*1024 + (size_t)h*128 + tid*2;
  float z0 = zb[zoff], z1 = zb[zoff+1];
  float n0 = norm_w[tid*2], n1 = norm_w[tid*2+1];
  float r0 = ov.x*inv*n0 * z0/(1.f+expf(-z0));
  float r1 = ov.y*inv*n1 * z1/(1.f+expf(-z1));
  og[zoff]   = r0;
  og[zoff+1] = r1;
}

extern "C" void kernel_launch(void* const* d_in, const int* in_sizes, int n_in,
                              void* d_out, int out_size, void* d_ws, size_t ws_size,
                              hipStream_t stream) {
  const float* hs     = (const float*)d_in[0];
  const float* qkv_w  = (const float*)d_in[1];
  const float* z_w    = (const float*)d_in[2];
  const float* b_w    = (const float*)d_in[3];
  const float* a_w    = (const float*)d_in[4];
  const float* conv_w = (const float*)d_in[5];
  const float* dt_bias= (const float*)d_in[6];
  const float* A_log  = (const float*)d_in[7];
  const float* norm_w = (const float*)d_in[8];
  const float* out_w  = (const float*)d_in[9];
  float* out = (float*)d_out;

  char* wsp = (char*)d_ws;
  size_t off = 0;
  auto give = [&](size_t bytes)->char*{
    char* p = wsp + off; off += (bytes + 255) & ~(size_t)255; return p;
  };
  float* mixed = (float*)give((size_t)MROWS*CONV_DIM_*4);  // 48 MB
  float* zbuf  = (float*)give((size_t)MROWS*1024*4);       // 16 MB
  float* qb    = (float*)give((size_t)32*T_*128*4);
  float* kb    = (float*)give((size_t)32*T_*128*4);
  float* vb    = (float*)give((size_t)32*T_*128*4);
  float* gbuf  = (float*)give((size_t)32*T_*4);            // log-alpha
  float* beta  = (float*)give((size_t)32*T_*4);
  // mixed is dead after conv_route; reuse its space for ob and og.
  float* ob    = mixed;                                    // 16 MB (fits in 48)
  float* og    = mixed + (size_t)4*1024*1024;              // next 16 MB

  gemm_bt_kernel<<<dim3(CONV_DIM_/64, MROWS/64), dim3(256), 0, stream>>>(hs, qkv_w, mixed, MROWS, CONV_DIM_, HID_);
  gemm_bt_kernel<<<dim3(1024/64, MROWS/64), dim3(256), 0, stream>>>(hs, z_w, zbuf, MROWS, 1024, HID_);
  proj_ba_kernel<<<dim3(MROWS), dim3(128), 0, stream>>>(hs, b_w, a_w, dt_bias, A_log, gbuf, beta);
  conv_route_kernel<<<dim3((MROWS*CONV_DIM_)/256), dim3(256), 0, stream>>>(mixed, conv_w, qb, kb, vb);
  scan_chunk_kernel<<<dim3(256), dim3(256), 0, stream>>>(qb, kb, vb, gbuf, beta, ob);
  gnorm_kernel<<<dim3(32*T_), dim3(64), 0, stream>>>(ob, zbuf, norm_w, og);
  gemm_bt_kernel<<<dim3(1024/64, MROWS/64), dim3(256), 0, stream>>>(og, out_w, out, MROWS, 1024, HID_);
}

// Round 5
// 697.148 us; speedup vs baseline: 2.5875x; 1.9208x over previous
//
#include <hip/hip_runtime.h>

#define B_ 4
#define T_ 1024
#define HID_ 1024
#define H_ 8
#define CONV_DIM_ 3072
#define MROWS (B_*T_)

typedef __bf16 bf16x8 __attribute__((ext_vector_type(8)));
typedef float f32x4 __attribute__((ext_vector_type(4)));

static __device__ __forceinline__ unsigned short f2bf(float f) {
  unsigned u = __float_as_uint(f);
  unsigned r = u + 0x7fffu + ((u >> 16) & 1u);   // RNE
  return (unsigned short)(r >> 16);
}
static __device__ __forceinline__ float bfu2f(unsigned short v) {
  return __uint_as_float(((unsigned)v) << 16);
}

// fp32 -> bf16 elementwise
__global__ __launch_bounds__(256) void f2bf_kernel(
    const float* __restrict__ src, unsigned short* __restrict__ dst, int n) {
  int i = (blockIdx.x * 256 + threadIdx.x) * 4;
  if (i >= n) return;
  float4 v = *(const float4*)(src + i);
  ushort4 o;
  o.x = f2bf(v.x); o.y = f2bf(v.y); o.z = f2bf(v.z); o.w = f2bf(v.w);
  *(ushort4*)(dst + i) = o;
}

// fp32 -> (hi, lo) bf16 split: hi = bf16(x), lo = bf16(x - hi)
__global__ __launch_bounds__(256) void f2bf_split_kernel(
    const float* __restrict__ src, unsigned short* __restrict__ hi,
    unsigned short* __restrict__ lo, int n) {
  int i = (blockIdx.x * 256 + threadIdx.x) * 4;
  if (i >= n) return;
  float4 v = *(const float4*)(src + i);
  ushort4 h, l;
  h.x = f2bf(v.x); h.y = f2bf(v.y); h.z = f2bf(v.z); h.w = f2bf(v.w);
  l.x = f2bf(v.x - bfu2f(h.x));
  l.y = f2bf(v.y - bfu2f(h.y));
  l.z = f2bf(v.z - bfu2f(h.z));
  l.w = f2bf(v.w - bfu2f(h.w));
  *(ushort4*)(hi + i) = h;
  *(ushort4*)(lo + i) = l;
}

// Single-pass bf16 MFMA GEMM: C[M,N] = A[M,K] * W[N,K]^T. 128x128 tile, BK=32.
template<int OUT_BF16>
__global__ __launch_bounds__(256) void gemm_mfma_kernel(
    const unsigned short* __restrict__ A, const unsigned short* __restrict__ W,
    void* __restrict__ Cv, int M, int N, int K) {
  __shared__ __align__(16) unsigned short lA[128*32];
  __shared__ __align__(16) unsigned short lB[128*32];
  const int tid  = threadIdx.x;
  const int lane = tid & 63;
  const int wv   = tid >> 6;
  const int wm   = (wv >> 1) * 64;
  const int wn   = (wv & 1) * 64;
  const int m16  = lane & 15;
  const int quad = lane >> 4;
  const int bm = blockIdx.y * 128;
  const int bn = blockIdx.x * 128;

  f32x4 acc[4][4];
  #pragma unroll
  for (int i = 0; i < 4; ++i)
    #pragma unroll
    for (int j = 0; j < 4; ++j)
      acc[i][j] = (f32x4){0.f, 0.f, 0.f, 0.f};

  const int r0 = tid >> 2, c0 = tid & 3;
  const int r1 = r0 + 64;
  const int g0 = (c0 ^ (r0 & 3)) * 8;
  const int g1 = (c0 ^ (r1 & 3)) * 8;
  const unsigned short* Ar0 = A + (size_t)(bm + r0) * K + g0;
  const unsigned short* Ar1 = A + (size_t)(bm + r1) * K + g1;
  const unsigned short* Wr0 = W + (size_t)(bn + r0) * K + g0;
  const unsigned short* Wr1 = W + (size_t)(bn + r1) * K + g1;
  unsigned short* sA0 = &lA[(size_t)tid * 8];
  unsigned short* sA1 = &lA[(size_t)(tid + 256) * 8];
  unsigned short* sB0 = &lB[(size_t)tid * 8];
  unsigned short* sB1 = &lB[(size_t)(tid + 256) * 8];

  int offA[4], offB[4];
  #pragma unroll
  for (int i = 0; i < 4; ++i) {
    int ra = wm + i * 16 + m16;
    offA[i] = ra * 32 + (quad ^ (ra & 3)) * 8;
    int rb = wn + i * 16 + m16;
    offB[i] = rb * 32 + (quad ^ (rb & 3)) * 8;
  }

  for (int k0 = 0; k0 < K; k0 += 32) {
    uint4 a0 = *(const uint4*)(Ar0 + k0);
    uint4 a1 = *(const uint4*)(Ar1 + k0);
    uint4 b0 = *(const uint4*)(Wr0 + k0);
    uint4 b1 = *(const uint4*)(Wr1 + k0);
    *(uint4*)sA0 = a0;
    *(uint4*)sA1 = a1;
    *(uint4*)sB0 = b0;
    *(uint4*)sB1 = b1;
    __syncthreads();
    bf16x8 af[4], bfr[4];
    #pragma unroll
    for (int i = 0; i < 4; ++i) {
      af[i]  = *(const bf16x8*)&lA[offA[i]];
      bfr[i] = *(const bf16x8*)&lB[offB[i]];
    }
    #pragma unroll
    for (int mi = 0; mi < 4; ++mi)
      #pragma unroll
      for (int ni = 0; ni < 4; ++ni)
        acc[mi][ni] = __builtin_amdgcn_mfma_f32_16x16x32_bf16(af[mi], bfr[ni], acc[mi][ni], 0, 0, 0);
    __syncthreads();
  }

  #pragma unroll
  for (int mi = 0; mi < 4; ++mi) {
    #pragma unroll
    for (int r = 0; r < 4; ++r) {
      size_t row = (size_t)(bm + wm + mi * 16 + quad * 4 + r);
      #pragma unroll
      for (int ni = 0; ni < 4; ++ni) {
        int col = bn + wn + ni * 16 + m16;
        float val = acc[mi][ni][r];
        if (OUT_BF16) ((unsigned short*)Cv)[row * N + col] = f2bf(val);
        else          ((float*)Cv)[row * N + col] = val;
      }
    }
  }
}

// Split-precision MFMA GEMM: C = (Ahi+Alo)(Whi+Wlo)^T ~= Ahi*Whi + Ahi*Wlo + Alo*Whi.
// fp32 output. Same tile structure as gemm_mfma_kernel.
__global__ __launch_bounds__(256) void gemm_mfma_split_kernel(
    const unsigned short* __restrict__ Ahi, const unsigned short* __restrict__ Alo,
    const unsigned short* __restrict__ Whi, const unsigned short* __restrict__ Wlo,
    float* __restrict__ C, int M, int N, int K) {
  __shared__ __align__(16) unsigned short lAh[128*32];
  __shared__ __align__(16) unsigned short lAl[128*32];
  __shared__ __align__(16) unsigned short lBh[128*32];
  __shared__ __align__(16) unsigned short lBl[128*32];
  const int tid  = threadIdx.x;
  const int lane = tid & 63;
  const int wv   = tid >> 6;
  const int wm   = (wv >> 1) * 64;
  const int wn   = (wv & 1) * 64;
  const int m16  = lane & 15;
  const int quad = lane >> 4;
  const int bm = blockIdx.y * 128;
  const int bn = blockIdx.x * 128;

  f32x4 acc[4][4];
  #pragma unroll
  for (int i = 0; i < 4; ++i)
    #pragma unroll
    for (int j = 0; j < 4; ++j)
      acc[i][j] = (f32x4){0.f, 0.f, 0.f, 0.f};

  const int r0 = tid >> 2, c0 = tid & 3;
  const int r1 = r0 + 64;
  const int g0 = (c0 ^ (r0 & 3)) * 8;
  const int g1 = (c0 ^ (r1 & 3)) * 8;
  const size_t oA0 = (size_t)(bm + r0) * K + g0;
  const size_t oA1 = (size_t)(bm + r1) * K + g1;
  const size_t oB0 = (size_t)(bn + r0) * K + g0;
  const size_t oB1 = (size_t)(bn + r1) * K + g1;
  const int s0 = tid * 8, s1 = (tid + 256) * 8;

  int offA[4], offB[4];
  #pragma unroll
  for (int i = 0; i < 4; ++i) {
    int ra = wm + i * 16 + m16;
    offA[i] = ra * 32 + (quad ^ (ra & 3)) * 8;
    int rb = wn + i * 16 + m16;
    offB[i] = rb * 32 + (quad ^ (rb & 3)) * 8;
  }

  for (int k0 = 0; k0 < K; k0 += 32) {
    uint4 ah0 = *(const uint4*)(Ahi + oA0 + k0);
    uint4 ah1 = *(const uint4*)(Ahi + oA1 + k0);
    uint4 al0 = *(const uint4*)(Alo + oA0 + k0);
    uint4 al1 = *(const uint4*)(Alo + oA1 + k0);
    uint4 bh0 = *(const uint4*)(Whi + oB0 + k0);
    uint4 bh1 = *(const uint4*)(Whi + oB1 + k0);
    uint4 bl0 = *(const uint4*)(Wlo + oB0 + k0);
    uint4 bl1 = *(const uint4*)(Wlo + oB1 + k0);
    *(uint4*)&lAh[s0] = ah0;  *(uint4*)&lAh[s1] = ah1;
    *(uint4*)&lAl[s0] = al0;  *(uint4*)&lAl[s1] = al1;
    *(uint4*)&lBh[s0] = bh0;  *(uint4*)&lBh[s1] = bh1;
    *(uint4*)&lBl[s0] = bl0;  *(uint4*)&lBl[s1] = bl1;
    __syncthreads();
    bf16x8 afh[4], bfh[4];
    #pragma unroll
    for (int i = 0; i < 4; ++i) {
      afh[i] = *(const bf16x8*)&lAh[offA[i]];
      bfh[i] = *(const bf16x8*)&lBh[offB[i]];
    }
    // hi * hi
    #pragma unroll
    for (int mi = 0; mi < 4; ++mi)
      #pragma unroll
      for (int ni = 0; ni < 4; ++ni)
        acc[mi][ni] = __builtin_amdgcn_mfma_f32_16x16x32_bf16(afh[mi], bfh[ni], acc[mi][ni], 0, 0, 0);
    // hi * lo
    {
      bf16x8 bfl[4];
      #pragma unroll
      for (int i = 0; i < 4; ++i) bfl[i] = *(const bf16x8*)&lBl[offB[i]];
      #pragma unroll
      for (int mi = 0; mi < 4; ++mi)
        #pragma unroll
        for (int ni = 0; ni < 4; ++ni)
          acc[mi][ni] = __builtin_amdgcn_mfma_f32_16x16x32_bf16(afh[mi], bfl[ni], acc[mi][ni], 0, 0, 0);
    }
    // lo * hi
    {
      bf16x8 afl[4];
      #pragma unroll
      for (int i = 0; i < 4; ++i) afl[i] = *(const bf16x8*)&lAl[offA[i]];
      #pragma unroll
      for (int mi = 0; mi < 4; ++mi)
        #pragma unroll
        for (int ni = 0; ni < 4; ++ni)
          acc[mi][ni] = __builtin_amdgcn_mfma_f32_16x16x32_bf16(afl[mi], bfh[ni], acc[mi][ni], 0, 0, 0);
    }
    __syncthreads();
  }

  #pragma unroll
  for (int mi = 0; mi < 4; ++mi) {
    #pragma unroll
    for (int r = 0; r < 4; ++r) {
      size_t row = (size_t)(bm + wm + mi * 16 + quad * 4 + r);
      #pragma unroll
      for (int ni = 0; ni < 4; ++ni)
        C[row * N + bn + wn + ni * 16 + m16] = acc[mi][ni][r];
    }
  }
}

// bb/aa projections fused with beta / g=log(alpha). Reads fp32 hs (exact).
__global__ __launch_bounds__(128) void proj_ba_kernel(
    const float* __restrict__ hs, const float* __restrict__ b_w, const float* __restrict__ a_w,
    const float* __restrict__ dt_bias, const float* __restrict__ A_log,
    float* __restrict__ gout, float* __restrict__ beta) {
  const int bt = blockIdx.x;
  const int b = bt >> 10;
  const int t = bt & 1023;
  const int tid = threadIdx.x;
  const int grp = tid >> 3;
  const int l8 = tid & 7;
  const int h = grp & 7;
  const bool isA = grp >= 8;
  const float* w = (isA ? a_w : b_w) + (size_t)h * HID_;
  const float* x = hs + (size_t)bt * HID_;
  float s = 0.f;
  for (int e = l8*4; e < HID_; e += 32){
    float4 xv = *(const float4*)(x + e);
    float4 wv = *(const float4*)(w + e);
    s = fmaf(xv.x, wv.x, s);
    s = fmaf(xv.y, wv.y, s);
    s = fmaf(xv.z, wv.z, s);
    s = fmaf(xv.w, wv.w, s);
  }
  s += __shfl_xor(s,1); s += __shfl_xor(s,2); s += __shfl_xor(s,4);
  if (l8 == 0) {
    size_t o = ((size_t)(b*H_ + h))*T_ + t;
    if (!isA) {
      beta[o] = 1.f/(1.f+expf(-s));
    } else {
      float xx = s + dt_bias[h];
      float sp = fmaxf(xx,0.f) + log1pf(expf(-fabsf(xx)));   // softplus
      gout[o] = -expf(A_log[h]) * sp;                        // g = log(alpha)
    }
  }
}

// causal depthwise conv (K=4) on fp32 mixed (stride 3072) -> q/k/v [B,H,T,128] fp32
__global__ __launch_bounds__(256) void conv_route_kernel(
    const float* __restrict__ mixed, const float* __restrict__ conv_w,
    float* __restrict__ qb, float* __restrict__ kb, float* __restrict__ vb) {
  const int idx = blockIdx.x*256 + threadIdx.x;
  const int c = idx % CONV_DIM_;
  const int bt = idx / CONV_DIM_;
  const int t = bt & 1023;
  const int b = bt >> 10;
  float w[4];
  #pragma unroll
  for (int j=0;j<4;++j) w[j] = conv_w[c*4+j];
  float s = 0.f;
  #pragma unroll
  for (int j=0;j<4;++j){
    int tt = t - 3 + j;
    if (tt >= 0) s = fmaf(w[j], mixed[((size_t)(b*T_+tt))*CONV_DIM_ + c], s);
  }
  const int part = c >> 10;
  const int cc = c & 1023;
  const int hh = cc >> 7;
  const int d = cc & 127;
  float* dst = part==0 ? qb : (part==1 ? kb : vb);
  dst[(((size_t)(b*H_+hh))*T_ + t)*128 + d] = s;
}

// Chunked gated delta rule (WY form), C=64, fp32 — unchanged (verified round 3).
__global__ __launch_bounds__(256) void scan_chunk_kernel(
    const float* __restrict__ qb, const float* __restrict__ kb, const float* __restrict__ vb,
    const float* __restrict__ gbuf, const float* __restrict__ bbuf,
    float* __restrict__ ob) {
  const int bh = blockIdx.x >> 3;
  const int sl = blockIdx.x & 7;
  const int tid = threadIdx.x;

  __shared__ float sK[64][132];
  __shared__ float sA[64][68];
  __shared__ float sS0T[16][132];
  __shared__ float sW[64][17];
  __shared__ float lL[64];
  __shared__ float bL[64];

  const float* kg = kb + (size_t)bh*T_*128;
  const float* qg = qb + (size_t)bh*T_*128;
  const float* vg = vb + (size_t)bh*T_*128 + sl*16;
  const float* gg = gbuf + (size_t)bh*T_;
  const float* beg = bbuf + (size_t)bh*T_;
  float* og = ob + (size_t)bh*T_*128 + sl*16;

  const int it = tid >> 4, jt = tid & 15;
  const int ro = tid >> 2, dg = (tid & 3) * 4;
  const int wv = tid >> 6, ln = tid & 63;
  const int dd = ln >> 4, rr = ln & 15;
  const int dsub = wv*4 + dd;
  const int dk0 = (tid >> 4) * 8, dcol = tid & 15;

  for (int z = tid; z < 16*132; z += 256) ((float*)sS0T)[z] = 0.f;

  for (int ch = 0; ch < 16; ++ch) {
    const int t0 = ch * 64;
    __syncthreads();

    #pragma unroll
    for (int i = 0; i < 8; ++i) {
      int f4 = tid + 256*i;
      int row = f4 >> 5, c = f4 & 31;
      float4 val = *(const float4*)(kg + (size_t)(t0+row)*128 + c*4);
      *(float4*)&sK[row][c*4] = val;
    }
    if (tid < 64) {
      float x = gg[t0 + tid];
      #pragma unroll
      for (int o = 1; o < 64; o <<= 1) {
        float y = __shfl_up(x, o);
        if (tid >= o) x += y;
      }
      lL[tid] = x;
      bL[tid] = beg[t0 + tid];
    }
    __syncthreads();

    {
      float acc[4][4] = {};
      if (jt <= it) {
        for (int kk = 0; kk < 128; kk += 4) {
          float4 ka[4], kc[4];
          #pragma unroll
          for (int r = 0; r < 4; ++r) {
            ka[r] = *(const float4*)&sK[it*4+r][kk];
            kc[r] = *(const float4*)&sK[jt*4+r][kk];
          }
          #pragma unroll
          for (int a = 0; a < 4; ++a)
            #pragma unroll
            for (int b = 0; b < 4; ++b) {
              acc[a][b] = fmaf(ka[a].x, kc[b].x, acc[a][b]);
              acc[a][b] = fmaf(ka[a].y, kc[b].y, acc[a][b]);
              acc[a][b] = fmaf(ka[a].z, kc[b].z, acc[a][b]);
              acc[a][b] = fmaf(ka[a].w, kc[b].w, acc[a][b]);
            }
        }
      }
      #pragma unroll
      for (int a = 0; a < 4; ++a) {
        int i = it*4 + a;
        float bi = bL[i], li = lL[i];
        #pragma unroll
        for (int b = 0; b < 4; ++b) {
          int j = jt*4 + b;
          sA[i][j] = (j < i) ? bi * __expf(li - lL[j]) * acc[a][b] : 0.f;
        }
      }
    }
    __syncthreads();

    {
      float a0=0,a1=0,a2=0,a3=0;
      for (int kk = 0; kk < 128; kk += 4) {
        float4 kv = *(const float4*)&sK[ro][kk];
        float4 s0 = *(const float4*)&sS0T[dg+0][kk];
        float4 s1 = *(const float4*)&sS0T[dg+1][kk];
        float4 s2 = *(const float4*)&sS0T[dg+2][kk];
        float4 s3 = *(const float4*)&sS0T[dg+3][kk];
        a0 = fmaf(kv.x,s0.x,fmaf(kv.y,s0.y,fmaf(kv.z,s0.z,fmaf(kv.w,s0.w,a0))));
        a1 = fmaf(kv.x,s1.x,fmaf(kv.y,s1.y,fmaf(kv.z,s1.z,fmaf(kv.w,s1.w,a1))));
        a2 = fmaf(kv.x,s2.x,fmaf(kv.y,s2.y,fmaf(kv.z,s2.z,fmaf(kv.w,s2.w,a2))));
        a3 = fmaf(kv.x,s3.x,fmaf(kv.y,s3.y,fmaf(kv.z,s3.z,fmaf(kv.w,s3.w,a3))));
      }
      float be = bL[ro], ga = __expf(lL[ro]);
      float cg = be * ga;
      float4 vvv = *(const float4*)(vg + (size_t)(t0+ro)*128 + dg);
      sW[ro][dg+0] = be*vvv.x - cg*a0;
      sW[ro][dg+1] = be*vvv.y - cg*a1;
      sW[ro][dg+2] = be*vvv.z - cg*a2;
      sW[ro][dg+3] = be*vvv.w - cg*a3;
    }
    __syncthreads();

    {
      float rh[4];
      #pragma unroll
      for (int m = 0; m < 4; ++m) rh[m] = sW[rr + 16*m][dsub];
      #pragma unroll
      for (int j = 0; j < 63; ++j) {
        int src = (dd << 4) | (j & 15);
        float wj = __shfl(rh[j >> 4], src);
        #pragma unroll
        for (int m = 0; m < 4; ++m)
          rh[m] = fmaf(-sA[rr + 16*m][j], wj, rh[m]);
      }
      #pragma unroll
      for (int m = 0; m < 4; ++m) sW[rr + 16*m][dsub] = rh[m];
    }
    __syncthreads();

    {
      float acc[4][4] = {};
      if (jt <= it) {
        for (int kk = 0; kk < 128; kk += 4) {
          float4 qa[4], kc[4];
          #pragma unroll
          for (int r = 0; r < 4; ++r) {
            qa[r] = *(const float4*)(qg + (size_t)(t0+it*4+r)*128 + kk);
            kc[r] = *(const float4*)&sK[jt*4+r][kk];
          }
          #pragma unroll
          for (int a = 0; a < 4; ++a)
            #pragma unroll
            for (int b = 0; b < 4; ++b) {
              acc[a][b] = fmaf(qa[a].x, kc[b].x, acc[a][b]);
              acc[a][b] = fmaf(qa[a].y, kc[b].y, acc[a][b]);
              acc[a][b] = fmaf(qa[a].z, kc[b].z, acc[a][b]);
              acc[a][b] = fmaf(qa[a].w, kc[b].w, acc[a][b]);
            }
        }
      }
      #pragma unroll
      for (int a = 0; a < 4; ++a) {
        int i = it*4 + a;
        float li = lL[i];
        #pragma unroll
        for (int b = 0; b < 4; ++b) {
          int j = jt*4 + b;
          sA[i][j] = (j <= i) ? __expf(li - lL[j]) * acc[a][b] : 0.f;
        }
      }
    }
    __syncthreads();

    {
      float q0=0,q1=0,q2=0,q3=0;
      for (int kk = 0; kk < 128; kk += 4) {
        float4 qv = *(const float4*)(qg + (size_t)(t0+ro)*128 + kk);
        float4 s0 = *(const float4*)&sS0T[dg+0][kk];
        float4 s1 = *(const float4*)&sS0T[dg+1][kk];
        float4 s2 = *(const float4*)&sS0T[dg+2][kk];
        float4 s3 = *(const float4*)&sS0T[dg+3][kk];
        q0 = fmaf(qv.x,s0.x,fmaf(qv.y,s0.y,fmaf(qv.z,s0.z,fmaf(qv.w,s0.w,q0))));
        q1 = fmaf(qv.x,s1.x,fmaf(qv.y,s1.y,fmaf(qv.z,s1.z,fmaf(qv.w,s1.w,q1))));
        q2 = fmaf(qv.x,s2.x,fmaf(qv.y,s2.y,fmaf(qv.z,s2.z,fmaf(qv.w,s2.w,q2))));
        q3 = fmaf(qv.x,s3.x,fmaf(qv.y,s3.y,fmaf(qv.z,s3.z,fmaf(qv.w,s3.w,q3))));
      }
      float w0=0,w1=0,w2=0,w3=0;
      for (int j = 0; j < 64; j += 4) {
        float4 bv = *(const float4*)&sA[ro][j];
        w0 = fmaf(bv.x, sW[j+0][dg+0], w0); w1 = fmaf(bv.x, sW[j+0][dg+1], w1);
        w2 = fmaf(bv.x, sW[j+0][dg+2], w2); w3 = fmaf(bv.x, sW[j+0][dg+3], w3);
        w0 = fmaf(bv.y, sW[j+1][dg+0], w0); w1 = fmaf(bv.y, sW[j+1][dg+1], w1);
        w2 = fmaf(bv.y, sW[j+1][dg+2], w2); w3 = fmaf(bv.y, sW[j+1][dg+3], w3);
        w0 = fmaf(bv.z, sW[j+2][dg+0], w0); w1 = fmaf(bv.z, sW[j+2][dg+1], w1);
        w2 = fmaf(bv.z, sW[j+2][dg+2], w2); w3 = fmaf(bv.z, sW[j+2][dg+3], w3);
        w0 = fmaf(bv.w, sW[j+3][dg+0], w0); w1 = fmaf(bv.w, sW[j+3][dg+1], w1);
        w2 = fmaf(bv.w, sW[j+3][dg+2], w2); w3 = fmaf(bv.w, sW[j+3][dg+3], w3);
      }
      float ga = __expf(lL[ro]);
      float4 o;
      o.x = fmaf(ga, q0, w0);
      o.y = fmaf(ga, q1, w1);
      o.z = fmaf(ga, q2, w2);
      o.w = fmaf(ga, q3, w3);
      *(float4*)(og + (size_t)(t0+ro)*128 + dg) = o;
    }
    __syncthreads();

    {
      float sc = __expf(lL[63] - lL[ro]);
      sW[ro][dg+0] *= sc;
      sW[ro][dg+1] *= sc;
      sW[ro][dg+2] *= sc;
      sW[ro][dg+3] *= sc;
    }
    __syncthreads();

    {
      float gC = __expf(lL[63]);
      float4 sa = *(const float4*)&sS0T[dcol][dk0];
      float4 sb = *(const float4*)&sS0T[dcol][dk0+4];
      sa.x*=gC; sa.y*=gC; sa.z*=gC; sa.w*=gC;
      sb.x*=gC; sb.y*=gC; sb.z*=gC; sb.w*=gC;
      for (int j = 0; j < 64; ++j) {
        float wvv = sW[j][dcol];
        float4 k1 = *(const float4*)&sK[j][dk0];
        float4 k2 = *(const float4*)&sK[j][dk0+4];
        sa.x = fmaf(k1.x, wvv, sa.x); sa.y = fmaf(k1.y, wvv, sa.y);
        sa.z = fmaf(k1.z, wvv, sa.z); sa.w = fmaf(k1.w, wvv, sa.w);
        sb.x = fmaf(k2.x, wvv, sb.x); sb.y = fmaf(k2.y, wvv, sb.y);
        sb.z = fmaf(k2.z, wvv, sb.z); sb.w = fmaf(k2.w, wvv, sb.w);
      }
      *(float4*)&sS0T[dcol][dk0]   = sa;
      *(float4*)&sS0T[dcol][dk0+4] = sb;
    }
  }
}

// rmsnorm(o)*norm_w*silu(z) -> bf16 og [B*T,1024]; z bf16 [B*T,1024]
__global__ __launch_bounds__(64) void gnorm_kernel(
    const float* __restrict__ ob, const unsigned short* __restrict__ zbb,
    const float* __restrict__ norm_w, unsigned short* __restrict__ og) {
  const int idx = blockIdx.x;        // bh*T + t
  const int t = idx & 1023;
  const int bh = idx >> 10;
  const int b = bh >> 3;
  const int h = bh & 7;
  const int tid = threadIdx.x;
  const float* o = ob + ((size_t)bh*T_ + t)*128;
  float2 ov = *(const float2*)(o + tid*2);
  float ss = fmaf(ov.x, ov.x, ov.y*ov.y);
  #pragma unroll
  for (int m=1; m<64; m<<=1) ss += __shfl_xor(ss, m);
  float inv = rsqrtf(ss*(1.f/128.f) + 1e-6f);
  size_t zoff = ((size_t)(b*T_+t))*1024 + (size_t)h*128 + tid*2;
  ushort2 zv = *(const ushort2*)(zbb + zoff);
  float z0 = bfu2f(zv.x), z1 = bfu2f(zv.y);
  float n0 = norm_w[tid*2], n1 = norm_w[tid*2+1];
  float r0 = ov.x*inv*n0 * z0/(1.f+expf(-z0));
  float r1 = ov.y*inv*n1 * z1/(1.f+expf(-z1));
  ushort2 ot;
  ot.x = f2bf(r0); ot.y = f2bf(r1);
  *(ushort2*)(og + zoff) = ot;
}

extern "C" void kernel_launch(void* const* d_in, const int* in_sizes, int n_in,
                              void* d_out, int out_size, void* d_ws, size_t ws_size,
                              hipStream_t stream) {
  const float* hs     = (const float*)d_in[0];
  const float* qkv_w  = (const float*)d_in[1];
  const float* z_w    = (const float*)d_in[2];
  const float* b_w    = (const float*)d_in[3];
  const float* a_w    = (const float*)d_in[4];
  const float* conv_w = (const float*)d_in[5];
  const float* dt_bias= (const float*)d_in[6];
  const float* A_log  = (const float*)d_in[7];
  const float* norm_w = (const float*)d_in[8];
  const float* out_w  = (const float*)d_in[9];
  float* out = (float*)d_out;

  char* wsp = (char*)d_ws;
  size_t off = 0;
  auto give = [&](size_t bytes)->char*{
    char* p = wsp + off; off += (bytes + 255) & ~(size_t)255; return p;
  };
  float* mixed  = (float*)give((size_t)MROWS*CONV_DIM_*4);  // 48 MB fp32 qkv
  unsigned short* zbuf = (unsigned short*)give((size_t)MROWS*1024*2);  // 8 MB bf16 z
  unsigned short* outw_bf = (unsigned short*)give((size_t)HID_*1024*2); // 2 MB
  float* qb    = (float*)give((size_t)32*T_*128*4);          // 16 MB
  float* kb    = (float*)give((size_t)32*T_*128*4);          // 16 MB
  float* vb    = (float*)give((size_t)32*T_*128*4);          // 16 MB
  float* gbuf  = (float*)give((size_t)32*T_*4);
  float* beta  = (float*)give((size_t)32*T_*4);
  // overlays (all consumers/producers strictly stream-ordered):
  unsigned short* hs_hi = (unsigned short*)kb;                       // 8 MB, dead before conv writes kb
  unsigned short* hs_lo = (unsigned short*)kb + (size_t)MROWS*HID_;  // 8 MB
  unsigned short* wc_hi = (unsigned short*)vb;                       // 6 MB, dead before conv writes vb
  unsigned short* wc_lo = (unsigned short*)vb + (size_t)CONV_DIM_*HID_; // 6 MB
  unsigned short* wz_bf = (unsigned short*)qb;                       // 2 MB, dead before conv writes qb
  float* ob = mixed;                                        // 16 MB over mixed (dead after conv)
  unsigned short* og = (unsigned short*)(mixed + (size_t)4*1024*1024); // 8 MB, next region of mixed

  // conversions
  f2bf_split_kernel<<<dim3(MROWS*HID_/1024), 256, 0, stream>>>(hs, hs_hi, hs_lo, MROWS*HID_);
  f2bf_split_kernel<<<dim3(CONV_DIM_*HID_/1024), 256, 0, stream>>>(qkv_w, wc_hi, wc_lo, CONV_DIM_*HID_);
  f2bf_kernel<<<dim3(1024*HID_/1024), 256, 0, stream>>>(z_w, wz_bf, 1024*HID_);
  f2bf_kernel<<<dim3(1024*HID_/1024), 256, 0, stream>>>(out_w, outw_bf, 1024*HID_);

  // qkv projection, split precision -> fp32 mixed [4096 x 3072]
  gemm_mfma_split_kernel<<<dim3(CONV_DIM_/128, MROWS/128), 256, 0, stream>>>(
      hs_hi, hs_lo, wc_hi, wc_lo, mixed, MROWS, CONV_DIM_, HID_);
  // z projection, single pass -> bf16 zbuf [4096 x 1024]
  gemm_mfma_kernel<1><<<dim3(1024/128, MROWS/128), 256, 0, stream>>>(
      hs_hi, wz_bf, zbuf, MROWS, 1024, HID_);
  proj_ba_kernel<<<dim3(MROWS), dim3(128), 0, stream>>>(hs, b_w, a_w, dt_bias, A_log, gbuf, beta);
  conv_route_kernel<<<dim3((MROWS*CONV_DIM_)/256), dim3(256), 0, stream>>>(mixed, conv_w, qb, kb, vb);
  scan_chunk_kernel<<<dim3(256), dim3(256), 0, stream>>>(qb, kb, vb, gbuf, beta, ob);
  gnorm_kernel<<<dim3(32*T_), dim3(64), 0, stream>>>(ob, zbuf, norm_w, og);
  gemm_mfma_kernel<0><<<dim3(1024/128, MROWS/128), 256, 0, stream>>>(og, outw_bf, out, MROWS, 1024, HID_);
}

// Round 6
// 545.347 us; speedup vs baseline: 3.3077x; 1.2784x over previous
//
#include <hip/hip_runtime.h>

#define B_ 4
#define T_ 1024
#define HID_ 1024
#define H_ 8
#define CONV_DIM_ 3072
#define MROWS (B_*T_)

typedef __bf16 bf16x8 __attribute__((ext_vector_type(8)));
typedef float f32x4 __attribute__((ext_vector_type(4)));

static __device__ __forceinline__ unsigned short f2bf(float f) {
  unsigned u = __float_as_uint(f);
  unsigned r = u + 0x7fffu + ((u >> 16) & 1u);   // RNE
  return (unsigned short)(r >> 16);
}
static __device__ __forceinline__ float bfu2f(unsigned short v) {
  return __uint_as_float(((unsigned)v) << 16);
}

// fp32 -> bf16 elementwise
__global__ __launch_bounds__(256) void f2bf_kernel(
    const float* __restrict__ src, unsigned short* __restrict__ dst, int n) {
  int i = (blockIdx.x * 256 + threadIdx.x) * 4;
  if (i >= n) return;
  float4 v = *(const float4*)(src + i);
  ushort4 o;
  o.x = f2bf(v.x); o.y = f2bf(v.y); o.z = f2bf(v.z); o.w = f2bf(v.w);
  *(ushort4*)(dst + i) = o;
}

// fp32 -> (hi, lo) bf16 split
__global__ __launch_bounds__(256) void f2bf_split_kernel(
    const float* __restrict__ src, unsigned short* __restrict__ hi,
    unsigned short* __restrict__ lo, int n) {
  int i = (blockIdx.x * 256 + threadIdx.x) * 4;
  if (i >= n) return;
  float4 v = *(const float4*)(src + i);
  ushort4 h, l;
  h.x = f2bf(v.x); h.y = f2bf(v.y); h.z = f2bf(v.z); h.w = f2bf(v.w);
  l.x = f2bf(v.x - bfu2f(h.x));
  l.y = f2bf(v.y - bfu2f(h.y));
  l.z = f2bf(v.z - bfu2f(h.z));
  l.w = f2bf(v.w - bfu2f(h.w));
  *(ushort4*)(hi + i) = h;
  *(ushort4*)(lo + i) = l;
}

// Single-pass bf16 MFMA GEMM: C[M,N] = A[M,K] * W[N,K]^T. 128x128 tile, BK=32.
template<int OUT_BF16>
__global__ __launch_bounds__(256) void gemm_mfma_kernel(
    const unsigned short* __restrict__ A, const unsigned short* __restrict__ W,
    void* __restrict__ Cv, int M, int N, int K) {
  __shared__ __align__(16) unsigned short lA[128*32];
  __shared__ __align__(16) unsigned short lB[128*32];
  const int tid  = threadIdx.x;
  const int lane = tid & 63;
  const int wv   = tid >> 6;
  const int wm   = (wv >> 1) * 64;
  const int wn   = (wv & 1) * 64;
  const int m16  = lane & 15;
  const int quad = lane >> 4;
  const int bm = blockIdx.y * 128;
  const int bn = blockIdx.x * 128;

  f32x4 acc[4][4];
  #pragma unroll
  for (int i = 0; i < 4; ++i)
    #pragma unroll
    for (int j = 0; j < 4; ++j)
      acc[i][j] = (f32x4){0.f, 0.f, 0.f, 0.f};

  const int r0 = tid >> 2, c0 = tid & 3;
  const int r1 = r0 + 64;
  const int g0 = (c0 ^ (r0 & 3)) * 8;
  const int g1 = (c0 ^ (r1 & 3)) * 8;
  const unsigned short* Ar0 = A + (size_t)(bm + r0) * K + g0;
  const unsigned short* Ar1 = A + (size_t)(bm + r1) * K + g1;
  const unsigned short* Wr0 = W + (size_t)(bn + r0) * K + g0;
  const unsigned short* Wr1 = W + (size_t)(bn + r1) * K + g1;
  unsigned short* sA0 = &lA[(size_t)tid * 8];
  unsigned short* sA1 = &lA[(size_t)(tid + 256) * 8];
  unsigned short* sB0 = &lB[(size_t)tid * 8];
  unsigned short* sB1 = &lB[(size_t)(tid + 256) * 8];

  int offA[4], offB[4];
  #pragma unroll
  for (int i = 0; i < 4; ++i) {
    int ra = wm + i * 16 + m16;
    offA[i] = ra * 32 + (quad ^ (ra & 3)) * 8;
    int rb = wn + i * 16 + m16;
    offB[i] = rb * 32 + (quad ^ (rb & 3)) * 8;
  }

  for (int k0 = 0; k0 < K; k0 += 32) {
    uint4 a0 = *(const uint4*)(Ar0 + k0);
    uint4 a1 = *(const uint4*)(Ar1 + k0);
    uint4 b0 = *(const uint4*)(Wr0 + k0);
    uint4 b1 = *(const uint4*)(Wr1 + k0);
    *(uint4*)sA0 = a0;
    *(uint4*)sA1 = a1;
    *(uint4*)sB0 = b0;
    *(uint4*)sB1 = b1;
    __syncthreads();
    bf16x8 af[4], bfr[4];
    #pragma unroll
    for (int i = 0; i < 4; ++i) {
      af[i]  = *(const bf16x8*)&lA[offA[i]];
      bfr[i] = *(const bf16x8*)&lB[offB[i]];
    }
    #pragma unroll
    for (int mi = 0; mi < 4; ++mi)
      #pragma unroll
      for (int ni = 0; ni < 4; ++ni)
        acc[mi][ni] = __builtin_amdgcn_mfma_f32_16x16x32_bf16(af[mi], bfr[ni], acc[mi][ni], 0, 0, 0);
    __syncthreads();
  }

  #pragma unroll
  for (int mi = 0; mi < 4; ++mi) {
    #pragma unroll
    for (int r = 0; r < 4; ++r) {
      size_t row = (size_t)(bm + wm + mi * 16 + quad * 4 + r);
      #pragma unroll
      for (int ni = 0; ni < 4; ++ni) {
        int col = bn + wn + ni * 16 + m16;
        float val = acc[mi][ni][r];
        if (OUT_BF16) ((unsigned short*)Cv)[row * N + col] = f2bf(val);
        else          ((float*)Cv)[row * N + col] = val;
      }
    }
  }
}

// Split-precision MFMA GEMM: C ~= Ahi*Whi + Ahi*Wlo + Alo*Whi. fp32 out.
__global__ __launch_bounds__(256) void gemm_mfma_split_kernel(
    const unsigned short* __restrict__ Ahi, const unsigned short* __restrict__ Alo,
    const unsigned short* __restrict__ Whi, const unsigned short* __restrict__ Wlo,
    float* __restrict__ C, int M, int N, int K) {
  __shared__ __align__(16) unsigned short lAh[128*32];
  __shared__ __align__(16) unsigned short lAl[128*32];
  __shared__ __align__(16) unsigned short lBh[128*32];
  __shared__ __align__(16) unsigned short lBl[128*32];
  const int tid  = threadIdx.x;
  const int lane = tid & 63;
  const int wv   = tid >> 6;
  const int wm   = (wv >> 1) * 64;
  const int wn   = (wv & 1) * 64;
  const int m16  = lane & 15;
  const int quad = lane >> 4;
  const int bm = blockIdx.y * 128;
  const int bn = blockIdx.x * 128;

  f32x4 acc[4][4];
  #pragma unroll
  for (int i = 0; i < 4; ++i)
    #pragma unroll
    for (int j = 0; j < 4; ++j)
      acc[i][j] = (f32x4){0.f, 0.f, 0.f, 0.f};

  const int r0 = tid >> 2, c0 = tid & 3;
  const int r1 = r0 + 64;
  const int g0 = (c0 ^ (r0 & 3)) * 8;
  const int g1 = (c0 ^ (r1 & 3)) * 8;
  const size_t oA0 = (size_t)(bm + r0) * K + g0;
  const size_t oA1 = (size_t)(bm + r1) * K + g1;
  const size_t oB0 = (size_t)(bn + r0) * K + g0;
  const size_t oB1 = (size_t)(bn + r1) * K + g1;
  const int s0 = tid * 8, s1 = (tid + 256) * 8;

  int offA[4], offB[4];
  #pragma unroll
  for (int i = 0; i < 4; ++i) {
    int ra = wm + i * 16 + m16;
    offA[i] = ra * 32 + (quad ^ (ra & 3)) * 8;
    int rb = wn + i * 16 + m16;
    offB[i] = rb * 32 + (quad ^ (rb & 3)) * 8;
  }

  for (int k0 = 0; k0 < K; k0 += 32) {
    uint4 ah0 = *(const uint4*)(Ahi + oA0 + k0);
    uint4 ah1 = *(const uint4*)(Ahi + oA1 + k0);
    uint4 al0 = *(const uint4*)(Alo + oA0 + k0);
    uint4 al1 = *(const uint4*)(Alo + oA1 + k0);
    uint4 bh0 = *(const uint4*)(Whi + oB0 + k0);
    uint4 bh1 = *(const uint4*)(Whi + oB1 + k0);
    uint4 bl0 = *(const uint4*)(Wlo + oB0 + k0);
    uint4 bl1 = *(const uint4*)(Wlo + oB1 + k0);
    *(uint4*)&lAh[s0] = ah0;  *(uint4*)&lAh[s1] = ah1;
    *(uint4*)&lAl[s0] = al0;  *(uint4*)&lAl[s1] = al1;
    *(uint4*)&lBh[s0] = bh0;  *(uint4*)&lBh[s1] = bh1;
    *(uint4*)&lBl[s0] = bl0;  *(uint4*)&lBl[s1] = bl1;
    __syncthreads();
    bf16x8 afh[4], bfh[4];
    #pragma unroll
    for (int i = 0; i < 4; ++i) {
      afh[i] = *(const bf16x8*)&lAh[offA[i]];
      bfh[i] = *(const bf16x8*)&lBh[offB[i]];
    }
    #pragma unroll
    for (int mi = 0; mi < 4; ++mi)
      #pragma unroll
      for (int ni = 0; ni < 4; ++ni)
        acc[mi][ni] = __builtin_amdgcn_mfma_f32_16x16x32_bf16(afh[mi], bfh[ni], acc[mi][ni], 0, 0, 0);
    {
      bf16x8 bfl[4];
      #pragma unroll
      for (int i = 0; i < 4; ++i) bfl[i] = *(const bf16x8*)&lBl[offB[i]];
      #pragma unroll
      for (int mi = 0; mi < 4; ++mi)
        #pragma unroll
        for (int ni = 0; ni < 4; ++ni)
          acc[mi][ni] = __builtin_amdgcn_mfma_f32_16x16x32_bf16(afh[mi], bfl[ni], acc[mi][ni], 0, 0, 0);
    }
    {
      bf16x8 afl[4];
      #pragma unroll
      for (int i = 0; i < 4; ++i) afl[i] = *(const bf16x8*)&lAl[offA[i]];
      #pragma unroll
      for (int mi = 0; mi < 4; ++mi)
        #pragma unroll
        for (int ni = 0; ni < 4; ++ni)
          acc[mi][ni] = __builtin_amdgcn_mfma_f32_16x16x32_bf16(afl[mi], bfh[ni], acc[mi][ni], 0, 0, 0);
    }
    __syncthreads();
  }

  #pragma unroll
  for (int mi = 0; mi < 4; ++mi) {
    #pragma unroll
    for (int r = 0; r < 4; ++r) {
      size_t row = (size_t)(bm + wm + mi * 16 + quad * 4 + r);
      #pragma unroll
      for (int ni = 0; ni < 4; ++ni)
        C[row * N + bn + wn + ni * 16 + m16] = acc[mi][ni][r];
    }
  }
}

// bb/aa projections fused with beta / g=log(alpha). Reads fp32 hs (exact).
__global__ __launch_bounds__(128) void proj_ba_kernel(
    const float* __restrict__ hs, const float* __restrict__ b_w, const float* __restrict__ a_w,
    const float* __restrict__ dt_bias, const float* __restrict__ A_log,
    float* __restrict__ gout, float* __restrict__ beta) {
  const int bt = blockIdx.x;
  const int b = bt >> 10;
  const int t = bt & 1023;
  const int tid = threadIdx.x;
  const int grp = tid >> 3;
  const int l8 = tid & 7;
  const int h = grp & 7;
  const bool isA = grp >= 8;
  const float* w = (isA ? a_w : b_w) + (size_t)h * HID_;
  const float* x = hs + (size_t)bt * HID_;
  float s = 0.f;
  for (int e = l8*4; e < HID_; e += 32){
    float4 xv = *(const float4*)(x + e);
    float4 wv = *(const float4*)(w + e);
    s = fmaf(xv.x, wv.x, s);
    s = fmaf(xv.y, wv.y, s);
    s = fmaf(xv.z, wv.z, s);
    s = fmaf(xv.w, wv.w, s);
  }
  s += __shfl_xor(s,1); s += __shfl_xor(s,2); s += __shfl_xor(s,4);
  if (l8 == 0) {
    size_t o = ((size_t)(b*H_ + h))*T_ + t;
    if (!isA) {
      beta[o] = 1.f/(1.f+expf(-s));
    } else {
      float xx = s + dt_bias[h];
      float sp = fmaxf(xx,0.f) + log1pf(expf(-fabsf(xx)));   // softplus
      gout[o] = -expf(A_log[h]) * sp;                        // g = log(alpha)
    }
  }
}

// causal depthwise conv (K=4) on fp32 mixed -> q/k/v [B,H,T,128] fp32
__global__ __launch_bounds__(256) void conv_route_kernel(
    const float* __restrict__ mixed, const float* __restrict__ conv_w,
    float* __restrict__ qb, float* __restrict__ kb, float* __restrict__ vb) {
  const int idx = blockIdx.x*256 + threadIdx.x;
  const int c = idx % CONV_DIM_;
  const int bt = idx / CONV_DIM_;
  const int t = bt & 1023;
  const int b = bt >> 10;
  float w[4];
  #pragma unroll
  for (int j=0;j<4;++j) w[j] = conv_w[c*4+j];
  float s = 0.f;
  #pragma unroll
  for (int j=0;j<4;++j){
    int tt = t - 3 + j;
    if (tt >= 0) s = fmaf(w[j], mixed[((size_t)(b*T_+tt))*CONV_DIM_ + c], s);
  }
  const int part = c >> 10;
  const int cc = c & 1023;
  const int hh = cc >> 7;
  const int d = cc & 127;
  float* dst = part==0 ? qb : (part==1 ? kb : vb);
  dst[(((size_t)(b*H_+hh))*T_ + t)*128 + d] = s;
}

// Parallel A/B precompute: 512 blocks = (bh, chunk).
// A = strict-lower(beta_i exp(li-lj) k_i.k_j); B = incl-lower(exp(li-lj) q_i.k_j).
__global__ __launch_bounds__(256) void scan_ab_kernel(
    const float* __restrict__ qb, const float* __restrict__ kb,
    const float* __restrict__ gbuf, const float* __restrict__ bbuf,
    float* __restrict__ Ag, float* __restrict__ Bg) {
  const int blk = blockIdx.x;
  const int bh = blk >> 4;
  const int ch = blk & 15;
  const int t0 = ch * 64;
  const int tid = threadIdx.x;
  __shared__ float sK[64][132];
  __shared__ float lL[64];
  __shared__ float bL[64];
  const float* kg = kb + (size_t)bh*T_*128;
  const float* qg = qb + (size_t)bh*T_*128;
  float* Ao = Ag + (size_t)blk*4096;
  float* Bo = Bg + (size_t)blk*4096;

  #pragma unroll
  for (int i = 0; i < 8; ++i) {
    int f4 = tid + 256*i;
    int row = f4 >> 5, c = f4 & 31;
    *(float4*)&sK[row][c*4] = *(const float4*)(kg + (size_t)(t0+row)*128 + c*4);
  }
  if (tid < 64) {
    float x = gbuf[(size_t)bh*T_ + t0 + tid];
    #pragma unroll
    for (int o = 1; o < 64; o <<= 1) {
      float y = __shfl_up(x, o);
      if (tid >= o) x += y;
    }
    lL[tid] = x;
    bL[tid] = bbuf[(size_t)bh*T_ + t0 + tid];
  }
  __syncthreads();

  const int it = tid >> 4, jt = tid & 15;
  // A = K K^T (strict lower, decayed)
  {
    float acc[4][4] = {};
    if (jt <= it) {
      for (int kk = 0; kk < 128; kk += 4) {
        float4 ka[4], kc[4];
        #pragma unroll
        for (int r = 0; r < 4; ++r) {
          ka[r] = *(const float4*)&sK[it*4+r][kk];
          kc[r] = *(const float4*)&sK[jt*4+r][kk];
        }
        #pragma unroll
        for (int a = 0; a < 4; ++a)
          #pragma unroll
          for (int b = 0; b < 4; ++b) {
            acc[a][b] = fmaf(ka[a].x, kc[b].x, acc[a][b]);
            acc[a][b] = fmaf(ka[a].y, kc[b].y, acc[a][b]);
            acc[a][b] = fmaf(ka[a].z, kc[b].z, acc[a][b]);
            acc[a][b] = fmaf(ka[a].w, kc[b].w, acc[a][b]);
          }
      }
    }
    #pragma unroll
    for (int a = 0; a < 4; ++a) {
      int i = it*4 + a;
      float bi = bL[i], li = lL[i];
      #pragma unroll
      for (int b = 0; b < 4; ++b) {
        int j = jt*4 + b;
        Ao[i*64 + j] = (j < i) ? bi * __expf(li - lL[j]) * acc[a][b] : 0.f;
      }
    }
  }
  // B = Q K^T (inclusive lower, decayed)
  {
    float acc[4][4] = {};
    if (jt <= it) {
      for (int kk = 0; kk < 128; kk += 4) {
        float4 qa[4], kc[4];
        #pragma unroll
        for (int r = 0; r < 4; ++r) {
          qa[r] = *(const float4*)(qg + (size_t)(t0+it*4+r)*128 + kk);
          kc[r] = *(const float4*)&sK[jt*4+r][kk];
        }
        #pragma unroll
        for (int a = 0; a < 4; ++a)
          #pragma unroll
          for (int b = 0; b < 4; ++b) {
            acc[a][b] = fmaf(qa[a].x, kc[b].x, acc[a][b]);
            acc[a][b] = fmaf(qa[a].y, kc[b].y, acc[a][b]);
            acc[a][b] = fmaf(qa[a].z, kc[b].z, acc[a][b]);
            acc[a][b] = fmaf(qa[a].w, kc[b].w, acc[a][b]);
          }
      }
    }
    #pragma unroll
    for (int a = 0; a < 4; ++a) {
      int i = it*4 + a;
      float li = lL[i];
      #pragma unroll
      for (int b = 0; b < 4; ++b) {
        int j = jt*4 + b;
        Bo[i*64 + j] = (j <= i) ? __expf(li - lL[j]) * acc[a][b] : 0.f;
      }
    }
  }
}

// Sequential chunked scan: loads A/B precomputed; fuses K.S0 and Q.S0 phases.
// 256 blocks = 32 bh x 8 dv-slices(16); 256 threads.
__global__ __launch_bounds__(256) void scan_seq_kernel(
    const float* __restrict__ qb, const float* __restrict__ kb, const float* __restrict__ vb,
    const float* __restrict__ gbuf, const float* __restrict__ bbuf,
    const float* __restrict__ Ag, const float* __restrict__ Bg,
    float* __restrict__ ob) {
  const int bh = blockIdx.x >> 3;
  const int sl = blockIdx.x & 7;
  const int tid = threadIdx.x;

  __shared__ float sK[64][132];
  __shared__ float sA[64][68];
  __shared__ float sBB[64][68];
  __shared__ float sS0T[16][132];
  __shared__ float sW[64][20];
  __shared__ float lL[64];
  __shared__ float bL[64];

  const float* kg = kb + (size_t)bh*T_*128;
  const float* qg = qb + (size_t)bh*T_*128;
  const float* vg = vb + (size_t)bh*T_*128 + sl*16;
  const float* gg = gbuf + (size_t)bh*T_;
  const float* beg = bbuf + (size_t)bh*T_;
  float* og = ob + (size_t)bh*T_*128 + sl*16;

  const int ro = tid >> 2, dg = (tid & 3) * 4;     // row phases
  const int wv = tid >> 6, ln = tid & 63;          // subst
  const int dd = ln >> 4, rr = ln & 15;
  const int dsub = wv*4 + dd;
  const int dk0 = (tid >> 4) * 8, dcol = tid & 15; // S0-update

  for (int z = tid; z < 16*132; z += 256) ((float*)sS0T)[z] = 0.f;

  for (int ch = 0; ch < 16; ++ch) {
    const int t0 = ch * 64;
    const float* Ao = Ag + ((size_t)(bh*16 + ch))*4096;
    const float* Bo = Bg + ((size_t)(bh*16 + ch))*4096;
    __syncthreads();

    // stage K, A, B, cumsum
    #pragma unroll
    for (int i = 0; i < 8; ++i) {
      int f4 = tid + 256*i;
      int row = f4 >> 5, c = f4 & 31;
      *(float4*)&sK[row][c*4] = *(const float4*)(kg + (size_t)(t0+row)*128 + c*4);
    }
    #pragma unroll
    for (int i = 0; i < 4; ++i) {
      int f4 = tid + 256*i;
      int row = f4 >> 4, c = (f4 & 15) * 4;
      *(float4*)&sA[row][c]  = *(const float4*)(Ao + row*64 + c);
      *(float4*)&sBB[row][c] = *(const float4*)(Bo + row*64 + c);
    }
    if (tid < 64) {
      float x = gg[t0 + tid];
      #pragma unroll
      for (int o = 1; o < 64; o <<= 1) {
        float y = __shfl_up(x, o);
        if (tid >= o) x += y;
      }
      lL[tid] = x;
      bL[tid] = beg[t0 + tid];
    }
    __syncthreads();

    // fused: kv = K.S0 (for RHS) and qs = Q.S0 (for O), one pass over S0
    float q0=0,q1=0,q2=0,q3=0;
    {
      float a0=0,a1=0,a2=0,a3=0;
      for (int kk = 0; kk < 128; kk += 4) {
        float4 s0 = *(const float4*)&sS0T[dg+0][kk];
        float4 s1 = *(const float4*)&sS0T[dg+1][kk];
        float4 s2 = *(const float4*)&sS0T[dg+2][kk];
        float4 s3 = *(const float4*)&sS0T[dg+3][kk];
        float4 kv = *(const float4*)&sK[ro][kk];
        float4 qv = *(const float4*)(qg + (size_t)(t0+ro)*128 + kk);
        a0 = fmaf(kv.x,s0.x,fmaf(kv.y,s0.y,fmaf(kv.z,s0.z,fmaf(kv.w,s0.w,a0))));
        a1 = fmaf(kv.x,s1.x,fmaf(kv.y,s1.y,fmaf(kv.z,s1.z,fmaf(kv.w,s1.w,a1))));
        a2 = fmaf(kv.x,s2.x,fmaf(kv.y,s2.y,fmaf(kv.z,s2.z,fmaf(kv.w,s2.w,a2))));
        a3 = fmaf(kv.x,s3.x,fmaf(kv.y,s3.y,fmaf(kv.z,s3.z,fmaf(kv.w,s3.w,a3))));
        q0 = fmaf(qv.x,s0.x,fmaf(qv.y,s0.y,fmaf(qv.z,s0.z,fmaf(qv.w,s0.w,q0))));
        q1 = fmaf(qv.x,s1.x,fmaf(qv.y,s1.y,fmaf(qv.z,s1.z,fmaf(qv.w,s1.w,q1))));
        q2 = fmaf(qv.x,s2.x,fmaf(qv.y,s2.y,fmaf(qv.z,s2.z,fmaf(qv.w,s2.w,q2))));
        q3 = fmaf(qv.x,s3.x,fmaf(qv.y,s3.y,fmaf(qv.z,s3.z,fmaf(qv.w,s3.w,q3))));
      }
      float be = bL[ro], ga = __expf(lL[ro]);
      float cg = be * ga;
      float4 vvv = *(const float4*)(vg + (size_t)(t0+ro)*128 + dg);
      float4 w;
      w.x = be*vvv.x - cg*a0;
      w.y = be*vvv.y - cg*a1;
      w.z = be*vvv.z - cg*a2;
      w.w = be*vvv.w - cg*a3;
      *(float4*)&sW[ro][dg] = w;
    }
    __syncthreads();

    // subst: W = (I+A)^-1 RHS  (wave-local, column-partitioned)
    {
      float rh[4];
      #pragma unroll
      for (int m = 0; m < 4; ++m) rh[m] = sW[rr + 16*m][dsub];
      #pragma unroll
      for (int j = 0; j < 63; ++j) {
        int src = (dd << 4) | (j & 15);
        float wj = __shfl(rh[j >> 4], src);
        #pragma unroll
        for (int m = 0; m < 4; ++m)
          rh[m] = fmaf(-sA[rr + 16*m][j], wj, rh[m]);
      }
      #pragma unroll
      for (int m = 0; m < 4; ++m) sW[rr + 16*m][dsub] = rh[m];
    }
    __syncthreads();

    // O = gamma*qs + B.W -> global
    {
      float w0=0,w1=0,w2=0,w3=0;
      for (int j = 0; j < 64; j += 4) {
        float4 bv = *(const float4*)&sBB[ro][j];
        float4 x0 = *(const float4*)&sW[j+0][dg & ~3];  // dg is multiple of 4
        float4 x1 = *(const float4*)&sW[j+1][dg & ~3];
        float4 x2 = *(const float4*)&sW[j+2][dg & ~3];
        float4 x3 = *(const float4*)&sW[j+3][dg & ~3];
        w0 = fmaf(bv.x,x0.x,fmaf(bv.y,x1.x,fmaf(bv.z,x2.x,fmaf(bv.w,x3.x,w0))));
        w1 = fmaf(bv.x,x0.y,fmaf(bv.y,x1.y,fmaf(bv.z,x2.y,fmaf(bv.w,x3.y,w1))));
        w2 = fmaf(bv.x,x0.z,fmaf(bv.y,x1.z,fmaf(bv.z,x2.z,fmaf(bv.w,x3.z,w2))));
        w3 = fmaf(bv.x,x0.w,fmaf(bv.y,x1.w,fmaf(bv.z,x2.w,fmaf(bv.w,x3.w,w3))));
      }
      float ga = __expf(lL[ro]);
      float4 o;
      o.x = fmaf(ga, q0, w0);
      o.y = fmaf(ga, q1, w1);
      o.z = fmaf(ga, q2, w2);
      o.w = fmaf(ga, q3, w3);
      *(float4*)(og + (size_t)(t0+ro)*128 + dg) = o;
    }
    __syncthreads();

    // scale W rows by exp(lC - l_j)
    {
      float sc = __expf(lL[63] - lL[ro]);
      float4 w = *(const float4*)&sW[ro][dg];
      w.x*=sc; w.y*=sc; w.z*=sc; w.w*=sc;
      *(float4*)&sW[ro][dg] = w;
    }
    __syncthreads();

    // S0 = gC*S0 + K^T Wscaled
    {
      float gC = __expf(lL[63]);
      float4 sa = *(const float4*)&sS0T[dcol][dk0];
      float4 sb = *(const float4*)&sS0T[dcol][dk0+4];
      sa.x*=gC; sa.y*=gC; sa.z*=gC; sa.w*=gC;
      sb.x*=gC; sb.y*=gC; sb.z*=gC; sb.w*=gC;
      for (int j = 0; j < 64; ++j) {
        float wvv = sW[j][dcol];
        float4 k1 = *(const float4*)&sK[j][dk0];
        float4 k2 = *(const float4*)&sK[j][dk0+4];
        sa.x = fmaf(k1.x, wvv, sa.x); sa.y = fmaf(k1.y, wvv, sa.y);
        sa.z = fmaf(k1.z, wvv, sa.z); sa.w = fmaf(k1.w, wvv, sa.w);
        sb.x = fmaf(k2.x, wvv, sb.x); sb.y = fmaf(k2.y, wvv, sb.y);
        sb.z = fmaf(k2.z, wvv, sb.z); sb.w = fmaf(k2.w, wvv, sb.w);
      }
      *(float4*)&sS0T[dcol][dk0]   = sa;
      *(float4*)&sS0T[dcol][dk0+4] = sb;
    }
  }
}

// rmsnorm(o)*norm_w*silu(z) -> bf16 og; z bf16
__global__ __launch_bounds__(64) void gnorm_kernel(
    const float* __restrict__ ob, const unsigned short* __restrict__ zbb,
    const float* __restrict__ norm_w, unsigned short* __restrict__ og) {
  const int idx = blockIdx.x;
  const int t = idx & 1023;
  const int bh = idx >> 10;
  const int b = bh >> 3;
  const int h = bh & 7;
  const int tid = threadIdx.x;
  const float* o = ob + ((size_t)bh*T_ + t)*128;
  float2 ov = *(const float2*)(o + tid*2);
  float ss = fmaf(ov.x, ov.x, ov.y*ov.y);
  #pragma unroll
  for (int m=1; m<64; m<<=1) ss += __shfl_xor(ss, m);
  float inv = rsqrtf(ss*(1.f/128.f) + 1e-6f);
  size_t zoff = ((size_t)(b*T_+t))*1024 + (size_t)h*128 + tid*2;
  ushort2 zv = *(const ushort2*)(zbb + zoff);
  float z0 = bfu2f(zv.x), z1 = bfu2f(zv.y);
  float n0 = norm_w[tid*2], n1 = norm_w[tid*2+1];
  float r0 = ov.x*inv*n0 * z0/(1.f+expf(-z0));
  float r1 = ov.y*inv*n1 * z1/(1.f+expf(-z1));
  ushort2 ot;
  ot.x = f2bf(r0); ot.y = f2bf(r1);
  *(ushort2*)(og + zoff) = ot;
}

extern "C" void kernel_launch(void* const* d_in, const int* in_sizes, int n_in,
                              void* d_out, int out_size, void* d_ws, size_t ws_size,
                              hipStream_t stream) {
  const float* hs     = (const float*)d_in[0];
  const float* qkv_w  = (const float*)d_in[1];
  const float* z_w    = (const float*)d_in[2];
  const float* b_w    = (const float*)d_in[3];
  const float* a_w    = (const float*)d_in[4];
  const float* conv_w = (const float*)d_in[5];
  const float* dt_bias= (const float*)d_in[6];
  const float* A_log  = (const float*)d_in[7];
  const float* norm_w = (const float*)d_in[8];
  const float* out_w  = (const float*)d_in[9];
  float* out = (float*)d_out;

  char* wsp = (char*)d_ws;
  size_t off = 0;
  auto give = [&](size_t bytes)->char*{
    char* p = wsp + off; off += (bytes + 255) & ~(size_t)255; return p;
  };
  float* mixed  = (float*)give((size_t)MROWS*CONV_DIM_*4);  // 48 MB fp32 qkv
  unsigned short* zbuf = (unsigned short*)give((size_t)MROWS*1024*2);  // 8 MB
  unsigned short* outw_bf = (unsigned short*)give((size_t)HID_*1024*2); // 2 MB
  float* qb    = (float*)give((size_t)32*T_*128*4);          // 16 MB
  float* kb    = (float*)give((size_t)32*T_*128*4);          // 16 MB
  float* vb    = (float*)give((size_t)32*T_*128*4);          // 16 MB
  float* gbuf  = (float*)give((size_t)32*T_*4);
  float* beta  = (float*)give((size_t)32*T_*4);
  // overlays within mixed (48 MB = 12M floats), all stream-ordered:
  unsigned short* hs_hi = (unsigned short*)kb;
  unsigned short* hs_lo = (unsigned short*)kb + (size_t)MROWS*HID_;
  unsigned short* wc_hi = (unsigned short*)vb;
  unsigned short* wc_lo = (unsigned short*)vb + (size_t)CONV_DIM_*HID_;
  unsigned short* wz_bf = (unsigned short*)qb;
  float* ob = mixed;                                              // [0,4M) floats
  unsigned short* og = (unsigned short*)(mixed + (size_t)4*1024*1024); // [4M,6M)
  float* Ag = mixed + (size_t)6*1024*1024;                        // [6M,8M) = 8 MB
  float* Bg = mixed + (size_t)8*1024*1024;                        // [8M,10M) = 8 MB

  f2bf_split_kernel<<<dim3(MROWS*HID_/1024), 256, 0, stream>>>(hs, hs_hi, hs_lo, MROWS*HID_);
  f2bf_split_kernel<<<dim3(CONV_DIM_*HID_/1024), 256, 0, stream>>>(qkv_w, wc_hi, wc_lo, CONV_DIM_*HID_);
  f2bf_kernel<<<dim3(1024*HID_/1024), 256, 0, stream>>>(z_w, wz_bf, 1024*HID_);
  f2bf_kernel<<<dim3(1024*HID_/1024), 256, 0, stream>>>(out_w, outw_bf, 1024*HID_);

  gemm_mfma_split_kernel<<<dim3(CONV_DIM_/128, MROWS/128), 256, 0, stream>>>(
      hs_hi, hs_lo, wc_hi, wc_lo, mixed, MROWS, CONV_DIM_, HID_);
  gemm_mfma_kernel<1><<<dim3(1024/128, MROWS/128), 256, 0, stream>>>(
      hs_hi, wz_bf, zbuf, MROWS, 1024, HID_);
  proj_ba_kernel<<<dim3(MROWS), dim3(128), 0, stream>>>(hs, b_w, a_w, dt_bias, A_log, gbuf, beta);
  conv_route_kernel<<<dim3((MROWS*CONV_DIM_)/256), dim3(256), 0, stream>>>(mixed, conv_w, qb, kb, vb);
  scan_ab_kernel<<<dim3(512), dim3(256), 0, stream>>>(qb, kb, gbuf, beta, Ag, Bg);
  scan_seq_kernel<<<dim3(256), dim3(256), 0, stream>>>(qb, kb, vb, gbuf, beta, Ag, Bg, ob);
  gnorm_kernel<<<dim3(32*T_), dim3(64), 0, stream>>>(ob, zbuf, norm_w, og);
  gemm_mfma_kernel<0><<<dim3(1024/128, MROWS/128), 256, 0, stream>>>(og, outw_bf, out, MROWS, 1024, HID_);
}

// Round 7
// 478.090 us; speedup vs baseline: 3.7730x; 1.1407x over previous
//
#include <hip/hip_runtime.h>

#define B_ 4
#define T_ 1024
#define HID_ 1024
#define H_ 8
#define CONV_DIM_ 3072
#define MROWS (B_*T_)

typedef __bf16 bf16x8 __attribute__((ext_vector_type(8)));
typedef float f32x4 __attribute__((ext_vector_type(4)));

static __device__ __forceinline__ unsigned short f2bf(float f) {
  unsigned u = __float_as_uint(f);
  unsigned r = u + 0x7fffu + ((u >> 16) & 1u);   // RNE
  return (unsigned short)(r >> 16);
}
static __device__ __forceinline__ float bfu2f(unsigned short v) {
  return __uint_as_float(((unsigned)v) << 16);
}

// fp32 -> bf16 elementwise
__global__ __launch_bounds__(256) void f2bf_kernel(
    const float* __restrict__ src, unsigned short* __restrict__ dst, int n) {
  int i = (blockIdx.x * 256 + threadIdx.x) * 4;
  if (i >= n) return;
  float4 v = *(const float4*)(src + i);
  ushort4 o;
  o.x = f2bf(v.x); o.y = f2bf(v.y); o.z = f2bf(v.z); o.w = f2bf(v.w);
  *(ushort4*)(dst + i) = o;
}

// fp32 -> (hi, lo) bf16 split
__global__ __launch_bounds__(256) void f2bf_split_kernel(
    const float* __restrict__ src, unsigned short* __restrict__ hi,
    unsigned short* __restrict__ lo, int n) {
  int i = (blockIdx.x * 256 + threadIdx.x) * 4;
  if (i >= n) return;
  float4 v = *(const float4*)(src + i);
  ushort4 h, l;
  h.x = f2bf(v.x); h.y = f2bf(v.y); h.z = f2bf(v.z); h.w = f2bf(v.w);
  l.x = f2bf(v.x - bfu2f(h.x));
  l.y = f2bf(v.y - bfu2f(h.y));
  l.z = f2bf(v.z - bfu2f(h.z));
  l.w = f2bf(v.w - bfu2f(h.w));
  *(ushort4*)(hi + i) = h;
  *(ushort4*)(lo + i) = l;
}

// Single-pass bf16 MFMA GEMM: C[M,N] = A[M,K] * W[N,K]^T. 128x128 tile, BK=32.
template<int OUT_BF16>
__global__ __launch_bounds__(256) void gemm_mfma_kernel(
    const unsigned short* __restrict__ A, const unsigned short* __restrict__ W,
    void* __restrict__ Cv, int M, int N, int K) {
  __shared__ __align__(16) unsigned short lA[128*32];
  __shared__ __align__(16) unsigned short lB[128*32];
  const int tid  = threadIdx.x;
  const int lane = tid & 63;
  const int wv   = tid >> 6;
  const int wm   = (wv >> 1) * 64;
  const int wn   = (wv & 1) * 64;
  const int m16  = lane & 15;
  const int quad = lane >> 4;
  const int bm = blockIdx.y * 128;
  const int bn = blockIdx.x * 128;

  f32x4 acc[4][4];
  #pragma unroll
  for (int i = 0; i < 4; ++i)
    #pragma unroll
    for (int j = 0; j < 4; ++j)
      acc[i][j] = (f32x4){0.f, 0.f, 0.f, 0.f};

  const int r0 = tid >> 2, c0 = tid & 3;
  const int r1 = r0 + 64;
  const int g0 = (c0 ^ (r0 & 3)) * 8;
  const int g1 = (c0 ^ (r1 & 3)) * 8;
  const unsigned short* Ar0 = A + (size_t)(bm + r0) * K + g0;
  const unsigned short* Ar1 = A + (size_t)(bm + r1) * K + g1;
  const unsigned short* Wr0 = W + (size_t)(bn + r0) * K + g0;
  const unsigned short* Wr1 = W + (size_t)(bn + r1) * K + g1;
  unsigned short* sA0 = &lA[(size_t)tid * 8];
  unsigned short* sA1 = &lA[(size_t)(tid + 256) * 8];
  unsigned short* sB0 = &lB[(size_t)tid * 8];
  unsigned short* sB1 = &lB[(size_t)(tid + 256) * 8];

  int offA[4], offB[4];
  #pragma unroll
  for (int i = 0; i < 4; ++i) {
    int ra = wm + i * 16 + m16;
    offA[i] = ra * 32 + (quad ^ (ra & 3)) * 8;
    int rb = wn + i * 16 + m16;
    offB[i] = rb * 32 + (quad ^ (rb & 3)) * 8;
  }

  for (int k0 = 0; k0 < K; k0 += 32) {
    uint4 a0 = *(const uint4*)(Ar0 + k0);
    uint4 a1 = *(const uint4*)(Ar1 + k0);
    uint4 b0 = *(const uint4*)(Wr0 + k0);
    uint4 b1 = *(const uint4*)(Wr1 + k0);
    *(uint4*)sA0 = a0;
    *(uint4*)sA1 = a1;
    *(uint4*)sB0 = b0;
    *(uint4*)sB1 = b1;
    __syncthreads();
    bf16x8 af[4], bfr[4];
    #pragma unroll
    for (int i = 0; i < 4; ++i) {
      af[i]  = *(const bf16x8*)&lA[offA[i]];
      bfr[i] = *(const bf16x8*)&lB[offB[i]];
    }
    #pragma unroll
    for (int mi = 0; mi < 4; ++mi)
      #pragma unroll
      for (int ni = 0; ni < 4; ++ni)
        acc[mi][ni] = __builtin_amdgcn_mfma_f32_16x16x32_bf16(af[mi], bfr[ni], acc[mi][ni], 0, 0, 0);
    __syncthreads();
  }

  #pragma unroll
  for (int mi = 0; mi < 4; ++mi) {
    #pragma unroll
    for (int r = 0; r < 4; ++r) {
      size_t row = (size_t)(bm + wm + mi * 16 + quad * 4 + r);
      #pragma unroll
      for (int ni = 0; ni < 4; ++ni) {
        int col = bn + wn + ni * 16 + m16;
        float val = acc[mi][ni][r];
        if (OUT_BF16) ((unsigned short*)Cv)[row * N + col] = f2bf(val);
        else          ((float*)Cv)[row * N + col] = val;
      }
    }
  }
}

// Split-precision MFMA GEMM: C ~= Ahi*Whi + Ahi*Wlo + Alo*Whi. fp32 out.
__global__ __launch_bounds__(256) void gemm_mfma_split_kernel(
    const unsigned short* __restrict__ Ahi, const unsigned short* __restrict__ Alo,
    const unsigned short* __restrict__ Whi, const unsigned short* __restrict__ Wlo,
    float* __restrict__ C, int M, int N, int K) {
  __shared__ __align__(16) unsigned short lAh[128*32];
  __shared__ __align__(16) unsigned short lAl[128*32];
  __shared__ __align__(16) unsigned short lBh[128*32];
  __shared__ __align__(16) unsigned short lBl[128*32];
  const int tid  = threadIdx.x;
  const int lane = tid & 63;
  const int wv   = tid >> 6;
  const int wm   = (wv >> 1) * 64;
  const int wn   = (wv & 1) * 64;
  const int m16  = lane & 15;
  const int quad = lane >> 4;
  const int bm = blockIdx.y * 128;
  const int bn = blockIdx.x * 128;

  f32x4 acc[4][4];
  #pragma unroll
  for (int i = 0; i < 4; ++i)
    #pragma unroll
    for (int j = 0; j < 4; ++j)
      acc[i][j] = (f32x4){0.f, 0.f, 0.f, 0.f};

  const int r0 = tid >> 2, c0 = tid & 3;
  const int r1 = r0 + 64;
  const int g0 = (c0 ^ (r0 & 3)) * 8;
  const int g1 = (c0 ^ (r1 & 3)) * 8;
  const size_t oA0 = (size_t)(bm + r0) * K + g0;
  const size_t oA1 = (size_t)(bm + r1) * K + g1;
  const size_t oB0 = (size_t)(bn + r0) * K + g0;
  const size_t oB1 = (size_t)(bn + r1) * K + g1;
  const int s0 = tid * 8, s1 = (tid + 256) * 8;

  int offA[4], offB[4];
  #pragma unroll
  for (int i = 0; i < 4; ++i) {
    int ra = wm + i * 16 + m16;
    offA[i] = ra * 32 + (quad ^ (ra & 3)) * 8;
    int rb = wn + i * 16 + m16;
    offB[i] = rb * 32 + (quad ^ (rb & 3)) * 8;
  }

  for (int k0 = 0; k0 < K; k0 += 32) {
    uint4 ah0 = *(const uint4*)(Ahi + oA0 + k0);
    uint4 ah1 = *(const uint4*)(Ahi + oA1 + k0);
    uint4 al0 = *(const uint4*)(Alo + oA0 + k0);
    uint4 al1 = *(const uint4*)(Alo + oA1 + k0);
    uint4 bh0 = *(const uint4*)(Whi + oB0 + k0);
    uint4 bh1 = *(const uint4*)(Whi + oB1 + k0);
    uint4 bl0 = *(const uint4*)(Wlo + oB0 + k0);
    uint4 bl1 = *(const uint4*)(Wlo + oB1 + k0);
    *(uint4*)&lAh[s0] = ah0;  *(uint4*)&lAh[s1] = ah1;
    *(uint4*)&lAl[s0] = al0;  *(uint4*)&lAl[s1] = al1;
    *(uint4*)&lBh[s0] = bh0;  *(uint4*)&lBh[s1] = bh1;
    *(uint4*)&lBl[s0] = bl0;  *(uint4*)&lBl[s1] = bl1;
    __syncthreads();
    bf16x8 afh[4], bfh[4];
    #pragma unroll
    for (int i = 0; i < 4; ++i) {
      afh[i] = *(const bf16x8*)&lAh[offA[i]];
      bfh[i] = *(const bf16x8*)&lBh[offB[i]];
    }
    #pragma unroll
    for (int mi = 0; mi < 4; ++mi)
      #pragma unroll
      for (int ni = 0; ni < 4; ++ni)
        acc[mi][ni] = __builtin_amdgcn_mfma_f32_16x16x32_bf16(afh[mi], bfh[ni], acc[mi][ni], 0, 0, 0);
    {
      bf16x8 bfl[4];
      #pragma unroll
      for (int i = 0; i < 4; ++i) bfl[i] = *(const bf16x8*)&lBl[offB[i]];
      #pragma unroll
      for (int mi = 0; mi < 4; ++mi)
        #pragma unroll
        for (int ni = 0; ni < 4; ++ni)
          acc[mi][ni] = __builtin_amdgcn_mfma_f32_16x16x32_bf16(afh[mi], bfl[ni], acc[mi][ni], 0, 0, 0);
    }
    {
      bf16x8 afl[4];
      #pragma unroll
      for (int i = 0; i < 4; ++i) afl[i] = *(const bf16x8*)&lAl[offA[i]];
      #pragma unroll
      for (int mi = 0; mi < 4; ++mi)
        #pragma unroll
        for (int ni = 0; ni < 4; ++ni)
          acc[mi][ni] = __builtin_amdgcn_mfma_f32_16x16x32_bf16(afl[mi], bfh[ni], acc[mi][ni], 0, 0, 0);
    }
    __syncthreads();
  }

  #pragma unroll
  for (int mi = 0; mi < 4; ++mi) {
    #pragma unroll
    for (int r = 0; r < 4; ++r) {
      size_t row = (size_t)(bm + wm + mi * 16 + quad * 4 + r);
      #pragma unroll
      for (int ni = 0; ni < 4; ++ni)
        C[row * N + bn + wn + ni * 16 + m16] = acc[mi][ni][r];
    }
  }
}

// bb/aa projections fused with beta / g=log(alpha). Reads fp32 hs (exact).
__global__ __launch_bounds__(128) void proj_ba_kernel(
    const float* __restrict__ hs, const float* __restrict__ b_w, const float* __restrict__ a_w,
    const float* __restrict__ dt_bias, const float* __restrict__ A_log,
    float* __restrict__ gout, float* __restrict__ beta) {
  const int bt = blockIdx.x;
  const int b = bt >> 10;
  const int t = bt & 1023;
  const int tid = threadIdx.x;
  const int grp = tid >> 3;
  const int l8 = tid & 7;
  const int h = grp & 7;
  const bool isA = grp >= 8;
  const float* w = (isA ? a_w : b_w) + (size_t)h * HID_;
  const float* x = hs + (size_t)bt * HID_;
  float s = 0.f;
  for (int e = l8*4; e < HID_; e += 32){
    float4 xv = *(const float4*)(x + e);
    float4 wv = *(const float4*)(w + e);
    s = fmaf(xv.x, wv.x, s);
    s = fmaf(xv.y, wv.y, s);
    s = fmaf(xv.z, wv.z, s);
    s = fmaf(xv.w, wv.w, s);
  }
  s += __shfl_xor(s,1); s += __shfl_xor(s,2); s += __shfl_xor(s,4);
  if (l8 == 0) {
    size_t o = ((size_t)(b*H_ + h))*T_ + t;
    if (!isA) {
      beta[o] = 1.f/(1.f+expf(-s));
    } else {
      float xx = s + dt_bias[h];
      float sp = fmaxf(xx,0.f) + log1pf(expf(-fabsf(xx)));   // softplus
      gout[o] = -expf(A_log[h]) * sp;                        // g = log(alpha)
    }
  }
}

// causal depthwise conv (K=4), 4 t-steps per thread (7 loads -> 4 outputs)
__global__ __launch_bounds__(256) void conv_route_kernel(
    const float* __restrict__ mixed, const float* __restrict__ conv_w,
    float* __restrict__ qb, float* __restrict__ kb, float* __restrict__ vb) {
  const int idx = blockIdx.x*256 + threadIdx.x;
  const int c = idx % CONV_DIM_;
  const int bt4 = idx / CONV_DIM_;
  const int b = bt4 >> 8;            // T/4 = 256 groups
  const int t0 = (bt4 & 255) * 4;
  float w0=conv_w[c*4],w1=conv_w[c*4+1],w2=conv_w[c*4+2],w3=conv_w[c*4+3];
  float x[7];
  #pragma unroll
  for (int j=0;j<7;++j){
    int tt = t0 - 3 + j;
    x[j] = (tt >= 0) ? mixed[((size_t)(b*T_+tt))*CONV_DIM_ + c] : 0.f;
  }
  const int part = c >> 10;
  const int cc = c & 1023;
  const int hh = cc >> 7;
  const int d = cc & 127;
  float* dst = part==0 ? qb : (part==1 ? kb : vb);
  size_t base = (((size_t)(b*H_+hh))*T_ + t0)*128 + d;
  #pragma unroll
  for (int i=0;i<4;++i){
    float s = fmaf(w0,x[i],fmaf(w1,x[i+1],fmaf(w2,x[i+2],w3*x[i+3])));
    dst[base + (size_t)i*128] = s;
  }
}

// Parallel precompute: 512 blocks = (bh, chunk).
// T = (I+A)^-1 (unit lower, A = strict-lower beta_i exp(li-lj) k_i.k_j), B = incl-lower decayed QK^T.
__global__ __launch_bounds__(256) void scan_ab_kernel(
    const float* __restrict__ qb, const float* __restrict__ kb,
    const float* __restrict__ gbuf, const float* __restrict__ bbuf,
    float* __restrict__ Tg, float* __restrict__ Bg) {
  const int blk = blockIdx.x;
  const int bh = blk >> 4;
  const int ch = blk & 15;
  const int t0 = ch * 64;
  const int tid = threadIdx.x;
  __shared__ float sK[64][132];
  __shared__ float sAA[64][68];
  __shared__ float lL[64];
  __shared__ float bL[64];
  const float* kg = kb + (size_t)bh*T_*128;
  const float* qg = qb + (size_t)bh*T_*128;
  float* To = Tg + (size_t)blk*4096;
  float* Bo = Bg + (size_t)blk*4096;

  #pragma unroll
  for (int i = 0; i < 8; ++i) {
    int f4 = tid + 256*i;
    int row = f4 >> 5, c = f4 & 31;
    *(float4*)&sK[row][c*4] = *(const float4*)(kg + (size_t)(t0+row)*128 + c*4);
  }
  if (tid < 64) {
    float x = gbuf[(size_t)bh*T_ + t0 + tid];
    #pragma unroll
    for (int o = 1; o < 64; o <<= 1) {
      float y = __shfl_up(x, o);
      if (tid >= o) x += y;
    }
    lL[tid] = x;
    bL[tid] = bbuf[(size_t)bh*T_ + t0 + tid];
  }
  __syncthreads();

  const int it = tid >> 4, jt = tid & 15;
  // A into LDS (strict lower, decayed); B to global
  {
    float acc[4][4] = {};
    if (jt <= it) {
      for (int kk = 0; kk < 128; kk += 4) {
        float4 ka[4], kc[4];
        #pragma unroll
        for (int r = 0; r < 4; ++r) {
          ka[r] = *(const float4*)&sK[it*4+r][kk];
          kc[r] = *(const float4*)&sK[jt*4+r][kk];
        }
        #pragma unroll
        for (int a = 0; a < 4; ++a)
          #pragma unroll
          for (int b = 0; b < 4; ++b) {
            acc[a][b] = fmaf(ka[a].x, kc[b].x, acc[a][b]);
            acc[a][b] = fmaf(ka[a].y, kc[b].y, acc[a][b]);
            acc[a][b] = fmaf(ka[a].z, kc[b].z, acc[a][b]);
            acc[a][b] = fmaf(ka[a].w, kc[b].w, acc[a][b]);
          }
      }
    }
    #pragma unroll
    for (int a = 0; a < 4; ++a) {
      int i = it*4 + a;
      float bi = bL[i], li = lL[i];
      #pragma unroll
      for (int b = 0; b < 4; ++b) {
        int j = jt*4 + b;
        sAA[i][j] = (j < i) ? bi * __expf(li - lL[j]) * acc[a][b] : 0.f;
      }
    }
  }
  {
    float acc[4][4] = {};
    if (jt <= it) {
      for (int kk = 0; kk < 128; kk += 4) {
        float4 qa[4], kc[4];
        #pragma unroll
        for (int r = 0; r < 4; ++r) {
          qa[r] = *(const float4*)(qg + (size_t)(t0+it*4+r)*128 + kk);
          kc[r] = *(const float4*)&sK[jt*4+r][kk];
        }
        #pragma unroll
        for (int a = 0; a < 4; ++a)
          #pragma unroll
          for (int b = 0; b < 4; ++b) {
            acc[a][b] = fmaf(qa[a].x, kc[b].x, acc[a][b]);
            acc[a][b] = fmaf(qa[a].y, kc[b].y, acc[a][b]);
            acc[a][b] = fmaf(qa[a].z, kc[b].z, acc[a][b]);
            acc[a][b] = fmaf(qa[a].w, kc[b].w, acc[a][b]);
          }
      }
    }
    #pragma unroll
    for (int a = 0; a < 4; ++a) {
      int i = it*4 + a;
      float li = lL[i];
      #pragma unroll
      for (int b = 0; b < 4; ++b) {
        int j = jt*4 + b;
        Bo[i*64 + j] = (j <= i) ? __expf(li - lL[j]) * acc[a][b] : 0.f;
      }
    }
  }
  __syncthreads();

  // invert (I+A): 4 waves x 16 cols, rows rr+4m per thread; wave-local chain
  {
    const int w = tid >> 6;
    const int ln = tid & 63;
    const int colc = w*16 + (ln & 15);
    const int rr = ln >> 4;
    float rh[16];
    #pragma unroll
    for (int m=0;m<16;++m) rh[m] = (rr + 4*m == colc) ? 1.f : 0.f;
    for (int j = 0; j < 63; ++j) {
      int src = ((j & 3) << 4) | (ln & 15);
      float wj = __shfl(rh[j >> 2], src);
      #pragma unroll
      for (int m=0;m<16;++m)
        rh[m] = fmaf(-sAA[rr + 4*m][j], wj, rh[m]);
    }
    #pragma unroll
    for (int m=0;m<16;++m)
      To[(rr + 4*m)*64 + colc] = rh[m];
  }
}

// Sequential chunked scan, 512 threads (8 waves = 2/SIMD), UT-transform form.
// 256 blocks = 32 bh x 8 dv-slices(16). All per-chunk matmuls, no serial chain.
__global__ __launch_bounds__(512) void scan_seq_kernel(
    const float* __restrict__ qb, const float* __restrict__ kb, const float* __restrict__ vb,
    const float* __restrict__ gbuf, const float* __restrict__ bbuf,
    const float* __restrict__ Tg, const float* __restrict__ Bg,
    float* __restrict__ ob) {
  const int bh = blockIdx.x >> 3;
  const int sl = blockIdx.x & 7;
  const int tid = threadIdx.x;

  __shared__ float sK[64][132];
  __shared__ float sQ[64][132];
  __shared__ float sT[64][68];
  __shared__ float sBB[64][68];
  __shared__ float sS0T[16][132];
  __shared__ float sW[64][20];    // RHS
  __shared__ float sW2[64][20];   // W = T*RHS
  __shared__ float sW3[64][20];   // W scaled for S0 update
  __shared__ float sQS[64][20];   // Q.S0
  __shared__ float lL[64];
  __shared__ float bL[64];

  const float* kg = kb + (size_t)bh*T_*128;
  const float* qg = qb + (size_t)bh*T_*128;
  const float* vg = vb + (size_t)bh*T_*128 + sl*16;
  const float* gg = gbuf + (size_t)bh*T_;
  const float* beg = bbuf + (size_t)bh*T_;
  float* og = ob + (size_t)bh*T_*128 + sl*16;

  const int ro  = tid >> 3;          // 0..63 row
  const int rem = tid & 7;
  const int kh  = rem >> 2;          // 0/1 k-half or j-half
  const int cg  = (rem & 3) * 4;     // col group (0,4,8,12)
  const int dcol = tid & 15, dk0 = (tid >> 4) * 4;   // S0-update decode

  for (int z = tid; z < 16*132; z += 512) ((float*)sS0T)[z] = 0.f;

  for (int ch = 0; ch < 16; ++ch) {
    const int t0 = ch * 64;
    const float* To = Tg + ((size_t)(bh*16 + ch))*4096;
    const float* Bo = Bg + ((size_t)(bh*16 + ch))*4096;
    __syncthreads();   // prev chunk's S0-update done; staging safe

    // ---- stage K, Q, T, B, cumsum
    #pragma unroll
    for (int i = 0; i < 4; ++i) {
      int f4 = tid + 512*i;
      int row = f4 >> 5, c = (f4 & 31) * 4;
      *(float4*)&sK[row][c] = *(const float4*)(kg + (size_t)(t0+row)*128 + c);
      *(float4*)&sQ[row][c] = *(const float4*)(qg + (size_t)(t0+row)*128 + c);
    }
    #pragma unroll
    for (int i = 0; i < 2; ++i) {
      int f4 = tid + 512*i;
      int row = f4 >> 4, c = (f4 & 15) * 4;
      *(float4*)&sT[row][c]  = *(const float4*)(To + row*64 + c);
      *(float4*)&sBB[row][c] = *(const float4*)(Bo + row*64 + c);
    }
    if (tid < 64) {
      float x = gg[t0 + tid];
      #pragma unroll
      for (int o = 1; o < 64; o <<= 1) {
        float y = __shfl_up(x, o);
        if (tid >= o) x += y;
      }
      lL[tid] = x;
      bL[tid] = beg[t0 + tid];
    }
    __syncthreads();

    // ---- F: kv = K.S0, qs = Q.S0 (k-half split, shfl-combined); RHS -> sW, qs -> sQS
    {
      float a0=0,a1=0,a2=0,a3=0,q0=0,q1=0,q2=0,q3=0;
      const int kbeg = kh * 64;
      for (int kk = kbeg; kk < kbeg + 64; kk += 4) {
        float4 s0 = *(const float4*)&sS0T[cg+0][kk];
        float4 s1 = *(const float4*)&sS0T[cg+1][kk];
        float4 s2 = *(const float4*)&sS0T[cg+2][kk];
        float4 s3 = *(const float4*)&sS0T[cg+3][kk];
        float4 kv = *(const float4*)&sK[ro][kk];
        float4 qv = *(const float4*)&sQ[ro][kk];
        a0 = fmaf(kv.x,s0.x,fmaf(kv.y,s0.y,fmaf(kv.z,s0.z,fmaf(kv.w,s0.w,a0))));
        a1 = fmaf(kv.x,s1.x,fmaf(kv.y,s1.y,fmaf(kv.z,s1.z,fmaf(kv.w,s1.w,a1))));
        a2 = fmaf(kv.x,s2.x,fmaf(kv.y,s2.y,fmaf(kv.z,s2.z,fmaf(kv.w,s2.w,a2))));
        a3 = fmaf(kv.x,s3.x,fmaf(kv.y,s3.y,fmaf(kv.z,s3.z,fmaf(kv.w,s3.w,a3))));
        q0 = fmaf(qv.x,s0.x,fmaf(qv.y,s0.y,fmaf(qv.z,s0.z,fmaf(qv.w,s0.w,q0))));
        q1 = fmaf(qv.x,s1.x,fmaf(qv.y,s1.y,fmaf(qv.z,s1.z,fmaf(qv.w,s1.w,q1))));
        q2 = fmaf(qv.x,s2.x,fmaf(qv.y,s2.y,fmaf(qv.z,s2.z,fmaf(qv.w,s2.w,q2))));
        q3 = fmaf(qv.x,s3.x,fmaf(qv.y,s3.y,fmaf(qv.z,s3.z,fmaf(qv.w,s3.w,q3))));
      }
      a0 += __shfl_xor(a0,4); a1 += __shfl_xor(a1,4);
      a2 += __shfl_xor(a2,4); a3 += __shfl_xor(a3,4);
      q0 += __shfl_xor(q0,4); q1 += __shfl_xor(q1,4);
      q2 += __shfl_xor(q2,4); q3 += __shfl_xor(q3,4);
      if (kh == 0) {
        float be = bL[ro], ga = __expf(lL[ro]);
        float cgf = be * ga;
        float4 vvv = *(const float4*)(vg + (size_t)(t0+ro)*128 + cg);
        float4 w;
        w.x = be*vvv.x - cgf*a0;
        w.y = be*vvv.y - cgf*a1;
        w.z = be*vvv.z - cgf*a2;
        w.w = be*vvv.w - cgf*a3;
        *(float4*)&sW[ro][cg] = w;
        float4 qs; qs.x=q0; qs.y=q1; qs.z=q2; qs.w=q3;
        *(float4*)&sQS[ro][cg] = qs;
      }
    }
    __syncthreads();

    // ---- W = T * RHS (j-half split); write sW2 (unscaled) and sW3 (scaled)
    {
      float w0=0,w1=0,w2=0,w3=0;
      const int jbeg = kh * 32;
      for (int j = jbeg; j < jbeg + 32; ++j) {
        float tv = sT[ro][j];
        float4 r = *(const float4*)&sW[j][cg];
        w0 = fmaf(tv, r.x, w0);
        w1 = fmaf(tv, r.y, w1);
        w2 = fmaf(tv, r.z, w2);
        w3 = fmaf(tv, r.w, w3);
      }
      w0 += __shfl_xor(w0,4); w1 += __shfl_xor(w1,4);
      w2 += __shfl_xor(w2,4); w3 += __shfl_xor(w3,4);
      if (kh == 0) {
        float4 w; w.x=w0; w.y=w1; w.z=w2; w.w=w3;
        *(float4*)&sW2[ro][cg] = w;
        float sc = __expf(lL[63] - lL[ro]);
        float4 ws; ws.x=w0*sc; ws.y=w1*sc; ws.z=w2*sc; ws.w=w3*sc;
        *(float4*)&sW3[ro][cg] = ws;
      }
    }
    __syncthreads();

    // ---- O = gamma*QS + B.W2 -> global (no barrier needed before U)
    {
      float w0=0,w1=0,w2=0,w3=0;
      const int jbeg = kh * 32;
      for (int j = jbeg; j < jbeg + 32; ++j) {
        float bv = sBB[ro][j];
        float4 r = *(const float4*)&sW2[j][cg];
        w0 = fmaf(bv, r.x, w0);
        w1 = fmaf(bv, r.y, w1);
        w2 = fmaf(bv, r.z, w2);
        w3 = fmaf(bv, r.w, w3);
      }
      w0 += __shfl_xor(w0,4); w1 += __shfl_xor(w1,4);
      w2 += __shfl_xor(w2,4); w3 += __shfl_xor(w3,4);
      if (kh == 0) {
        float ga = __expf(lL[ro]);
        float4 qs = *(const float4*)&sQS[ro][cg];
        float4 o;
        o.x = fmaf(ga, qs.x, w0);
        o.y = fmaf(ga, qs.y, w1);
        o.z = fmaf(ga, qs.z, w2);
        o.w = fmaf(ga, qs.w, w3);
        *(float4*)(og + (size_t)(t0+ro)*128 + cg) = o;
      }
    }

    // ---- U: S0 = gC*S0 + K^T W3 (each thread owns 4 S0 elements)
    {
      float gC = __expf(lL[63]);
      float4 sa = *(const float4*)&sS0T[dcol][dk0];
      sa.x*=gC; sa.y*=gC; sa.z*=gC; sa.w*=gC;
      for (int j = 0; j < 64; ++j) {
        float wvv = sW3[j][dcol];
        float4 k1 = *(const float4*)&sK[j][dk0];
        sa.x = fmaf(k1.x, wvv, sa.x); sa.y = fmaf(k1.y, wvv, sa.y);
        sa.z = fmaf(k1.z, wvv, sa.z); sa.w = fmaf(k1.w, wvv, sa.w);
      }
      *(float4*)&sS0T[dcol][dk0] = sa;
    }
  }
}

// rmsnorm(o)*norm_w*silu(z) -> bf16 og; z bf16
__global__ __launch_bounds__(64) void gnorm_kernel(
    const float* __restrict__ ob, const unsigned short* __restrict__ zbb,
    const float* __restrict__ norm_w, unsigned short* __restrict__ og) {
  const int idx = blockIdx.x;
  const int t = idx & 1023;
  const int bh = idx >> 10;
  const int b = bh >> 3;
  const int h = bh & 7;
  const int tid = threadIdx.x;
  const float* o = ob + ((size_t)bh*T_ + t)*128;
  float2 ov = *(const float2*)(o + tid*2);
  float ss = fmaf(ov.x, ov.x, ov.y*ov.y);
  #pragma unroll
  for (int m=1; m<64; m<<=1) ss += __shfl_xor(ss, m);
  float inv = rsqrtf(ss*(1.f/128.f) + 1e-6f);
  size_t zoff = ((size_t)(b*T_+t))*1024 + (size_t)h*128 + tid*2;
  ushort2 zv = *(const ushort2*)(zbb + zoff);
  float z0 = bfu2f(zv.x), z1 = bfu2f(zv.y);
  float n0 = norm_w[tid*2], n1 = norm_w[tid*2+1];
  float r0 = ov.x*inv*n0 * z0/(1.f+expf(-z0));
  float r1 = ov.y*inv*n1 * z1/(1.f+expf(-z1));
  ushort2 ot;
  ot.x = f2bf(r0); ot.y = f2bf(r1);
  *(ushort2*)(og + zoff) = ot;
}

extern "C" void kernel_launch(void* const* d_in, const int* in_sizes, int n_in,
                              void* d_out, int out_size, void* d_ws, size_t ws_size,
                              hipStream_t stream) {
  const float* hs     = (const float*)d_in[0];
  const float* qkv_w  = (const float*)d_in[1];
  const float* z_w    = (const float*)d_in[2];
  const float* b_w    = (const float*)d_in[3];
  const float* a_w    = (const float*)d_in[4];
  const float* conv_w = (const float*)d_in[5];
  const float* dt_bias= (const float*)d_in[6];
  const float* A_log  = (const float*)d_in[7];
  const float* norm_w = (const float*)d_in[8];
  const float* out_w  = (const float*)d_in[9];
  float* out = (float*)d_out;

  char* wsp = (char*)d_ws;
  size_t off = 0;
  auto give = [&](size_t bytes)->char*{
    char* p = wsp + off; off += (bytes + 255) & ~(size_t)255; return p;
  };
  float* mixed  = (float*)give((size_t)MROWS*CONV_DIM_*4);  // 48 MB fp32 qkv
  unsigned short* zbuf = (unsigned short*)give((size_t)MROWS*1024*2);  // 8 MB
  unsigned short* outw_bf = (unsigned short*)give((size_t)HID_*1024*2); // 2 MB
  float* qb    = (float*)give((size_t)32*T_*128*4);          // 16 MB
  float* kb    = (float*)give((size_t)32*T_*128*4);          // 16 MB
  float* vb    = (float*)give((size_t)32*T_*128*4);          // 16 MB
  float* gbuf  = (float*)give((size_t)32*T_*4);
  float* beta  = (float*)give((size_t)32*T_*4);
  // overlays within mixed (48 MB = 12M floats), all stream-ordered:
  unsigned short* hs_hi = (unsigned short*)kb;
  unsigned short* hs_lo = (unsigned short*)kb + (size_t)MROWS*HID_;
  unsigned short* wc_hi = (unsigned short*)vb;
  unsigned short* wc_lo = (unsigned short*)vb + (size_t)CONV_DIM_*HID_;
  unsigned short* wz_bf = (unsigned short*)qb;
  float* ob = mixed;                                              // [0,4M) floats
  unsigned short* og = (unsigned short*)(mixed + (size_t)4*1024*1024); // [4M,6M)
  float* Tg = mixed + (size_t)6*1024*1024;                        // [6M,8M) = 8 MB
  float* Bg = mixed + (size_t)8*1024*1024;                        // [8M,10M) = 8 MB

  f2bf_split_kernel<<<dim3(MROWS*HID_/1024), 256, 0, stream>>>(hs, hs_hi, hs_lo, MROWS*HID_);
  f2bf_split_kernel<<<dim3(CONV_DIM_*HID_/1024), 256, 0, stream>>>(qkv_w, wc_hi, wc_lo, CONV_DIM_*HID_);
  f2bf_kernel<<<dim3(1024*HID_/1024), 256, 0, stream>>>(z_w, wz_bf, 1024*HID_);
  f2bf_kernel<<<dim3(1024*HID_/1024), 256, 0, stream>>>(out_w, outw_bf, 1024*HID_);

  gemm_mfma_split_kernel<<<dim3(CONV_DIM_/128, MROWS/128), 256, 0, stream>>>(
      hs_hi, hs_lo, wc_hi, wc_lo, mixed, MROWS, CONV_DIM_, HID_);
  gemm_mfma_kernel<1><<<dim3(1024/128, MROWS/128), 256, 0, stream>>>(
      hs_hi, wz_bf, zbuf, MROWS, 1024, HID_);
  proj_ba_kernel<<<dim3(MROWS), dim3(128), 0, stream>>>(hs, b_w, a_w, dt_bias, A_log, gbuf, beta);
  conv_route_kernel<<<dim3((B_*256*CONV_DIM_)/256), dim3(256), 0, stream>>>(mixed, conv_w, qb, kb, vb);
  scan_ab_kernel<<<dim3(512), dim3(256), 0, stream>>>(qb, kb, gbuf, beta, Tg, Bg);
  scan_seq_kernel<<<dim3(256), dim3(512), 0, stream>>>(qb, kb, vb, gbuf, beta, Tg, Bg, ob);
  gnorm_kernel<<<dim3(32*T_), dim3(64), 0, stream>>>(ob, zbuf, norm_w, og);
  gemm_mfma_kernel<0><<<dim3(1024/128, MROWS/128), 256, 0, stream>>>(og, outw_bf, out, MROWS, 1024, HID_);
}

// Round 8
// 467.601 us; speedup vs baseline: 3.8577x; 1.0224x over previous
//
#include <hip/hip_runtime.h>

#define B_ 4
#define T_ 1024
#define HID_ 1024
#define H_ 8
#define CONV_DIM_ 3072
#define MROWS (B_*T_)

typedef __bf16 bf16x8 __attribute__((ext_vector_type(8)));
typedef float f32x4 __attribute__((ext_vector_type(4)));

static __device__ __forceinline__ unsigned short f2bf(float f) {
  unsigned u = __float_as_uint(f);
  unsigned r = u + 0x7fffu + ((u >> 16) & 1u);   // RNE
  return (unsigned short)(r >> 16);
}
static __device__ __forceinline__ float bfu2f(unsigned short v) {
  return __uint_as_float(((unsigned)v) << 16);
}

// async global->LDS 16B. LDS dest must be wave-uniform base + lane*16 (m104/m108).
static __device__ __forceinline__ void gld16(void* lds, const void* g) {
  __builtin_amdgcn_global_load_lds(
      (const __attribute__((address_space(1))) unsigned int*)g,
      (__attribute__((address_space(3))) unsigned int*)lds, 16, 0, 0);
}

// fp32 -> bf16 elementwise
__global__ __launch_bounds__(256) void f2bf_kernel(
    const float* __restrict__ src, unsigned short* __restrict__ dst, int n) {
  int i = (blockIdx.x * 256 + threadIdx.x) * 4;
  if (i >= n) return;
  float4 v = *(const float4*)(src + i);
  ushort4 o;
  o.x = f2bf(v.x); o.y = f2bf(v.y); o.z = f2bf(v.z); o.w = f2bf(v.w);
  *(ushort4*)(dst + i) = o;
}

// fp32 -> (hi, lo) bf16 split
__global__ __launch_bounds__(256) void f2bf_split_kernel(
    const float* __restrict__ src, unsigned short* __restrict__ hi,
    unsigned short* __restrict__ lo, int n) {
  int i = (blockIdx.x * 256 + threadIdx.x) * 4;
  if (i >= n) return;
  float4 v = *(const float4*)(src + i);
  ushort4 h, l;
  h.x = f2bf(v.x); h.y = f2bf(v.y); h.z = f2bf(v.z); h.w = f2bf(v.w);
  l.x = f2bf(v.x - bfu2f(h.x));
  l.y = f2bf(v.y - bfu2f(h.y));
  l.z = f2bf(v.z - bfu2f(h.z));
  l.w = f2bf(v.w - bfu2f(h.w));
  *(ushort4*)(hi + i) = h;
  *(ushort4*)(lo + i) = l;
}

// Single-pass bf16 MFMA GEMM: C[M,N] = A[M,K] * W[N,K]^T. 128x128 tile, BK=32.
// Staging via global_load_lds (async direct-to-LDS).
template<int OUT_BF16>
__global__ __launch_bounds__(256) void gemm_mfma_kernel(
    const unsigned short* __restrict__ A, const unsigned short* __restrict__ W,
    void* __restrict__ Cv, int M, int N, int K) {
  __shared__ __align__(16) unsigned short lA[128*32];
  __shared__ __align__(16) unsigned short lB[128*32];
  const int tid  = threadIdx.x;
  const int lane = tid & 63;
  const int wv   = tid >> 6;
  const int wm   = (wv >> 1) * 64;
  const int wn   = (wv & 1) * 64;
  const int m16  = lane & 15;
  const int quad = lane >> 4;
  const int bm = blockIdx.y * 128;
  const int bn = blockIdx.x * 128;

  f32x4 acc[4][4];
  #pragma unroll
  for (int i = 0; i < 4; ++i)
    #pragma unroll
    for (int j = 0; j < 4; ++j)
      acc[i][j] = (f32x4){0.f, 0.f, 0.f, 0.f};

  const int r0 = tid >> 2, c0 = tid & 3;
  const int r1 = r0 + 64;
  const int g0 = (c0 ^ (r0 & 3)) * 8;
  const int g1 = (c0 ^ (r1 & 3)) * 8;
  const unsigned short* Ar0 = A + (size_t)(bm + r0) * K + g0;
  const unsigned short* Ar1 = A + (size_t)(bm + r1) * K + g1;
  const unsigned short* Wr0 = W + (size_t)(bn + r0) * K + g0;
  const unsigned short* Wr1 = W + (size_t)(bn + r1) * K + g1;
  unsigned short* sA0 = &lA[(size_t)tid * 8];        // byte off = wv*1024 + lane*16
  unsigned short* sA1 = &lA[(size_t)(tid + 256) * 8];
  unsigned short* sB0 = &lB[(size_t)tid * 8];
  unsigned short* sB1 = &lB[(size_t)(tid + 256) * 8];

  int offA[4], offB[4];
  #pragma unroll
  for (int i = 0; i < 4; ++i) {
    int ra = wm + i * 16 + m16;
    offA[i] = ra * 32 + (quad ^ (ra & 3)) * 8;
    int rb = wn + i * 16 + m16;
    offB[i] = rb * 32 + (quad ^ (rb & 3)) * 8;
  }

  for (int k0 = 0; k0 < K; k0 += 32) {
    gld16(sA0, Ar0 + k0);
    gld16(sA1, Ar1 + k0);
    gld16(sB0, Wr0 + k0);
    gld16(sB1, Wr1 + k0);
    __syncthreads();    // drains vmcnt (incl. global_load_lds)
    bf16x8 af[4], bfr[4];
    #pragma unroll
    for (int i = 0; i < 4; ++i) {
      af[i]  = *(const bf16x8*)&lA[offA[i]];
      bfr[i] = *(const bf16x8*)&lB[offB[i]];
    }
    #pragma unroll
    for (int mi = 0; mi < 4; ++mi)
      #pragma unroll
      for (int ni = 0; ni < 4; ++ni)
        acc[mi][ni] = __builtin_amdgcn_mfma_f32_16x16x32_bf16(af[mi], bfr[ni], acc[mi][ni], 0, 0, 0);
    __syncthreads();
  }

  #pragma unroll
  for (int mi = 0; mi < 4; ++mi) {
    #pragma unroll
    for (int r = 0; r < 4; ++r) {
      size_t row = (size_t)(bm + wm + mi * 16 + quad * 4 + r);
      #pragma unroll
      for (int ni = 0; ni < 4; ++ni) {
        int col = bn + wn + ni * 16 + m16;
        float val = acc[mi][ni][r];
        if (OUT_BF16) ((unsigned short*)Cv)[row * N + col] = f2bf(val);
        else          ((float*)Cv)[row * N + col] = val;
      }
    }
  }
}

// Split-precision MFMA GEMM: C ~= Ahi*Whi + Ahi*Wlo + Alo*Whi. fp32 out.
// Staging via global_load_lds.
__global__ __launch_bounds__(256) void gemm_mfma_split_kernel(
    const unsigned short* __restrict__ Ahi, const unsigned short* __restrict__ Alo,
    const unsigned short* __restrict__ Whi, const unsigned short* __restrict__ Wlo,
    float* __restrict__ C, int M, int N, int K) {
  __shared__ __align__(16) unsigned short lAh[128*32];
  __shared__ __align__(16) unsigned short lAl[128*32];
  __shared__ __align__(16) unsigned short lBh[128*32];
  __shared__ __align__(16) unsigned short lBl[128*32];
  const int tid  = threadIdx.x;
  const int lane = tid & 63;
  const int wv   = tid >> 6;
  const int wm   = (wv >> 1) * 64;
  const int wn   = (wv & 1) * 64;
  const int m16  = lane & 15;
  const int quad = lane >> 4;
  const int bm = blockIdx.y * 128;
  const int bn = blockIdx.x * 128;

  f32x4 acc[4][4];
  #pragma unroll
  for (int i = 0; i < 4; ++i)
    #pragma unroll
    for (int j = 0; j < 4; ++j)
      acc[i][j] = (f32x4){0.f, 0.f, 0.f, 0.f};

  const int r0 = tid >> 2, c0 = tid & 3;
  const int r1 = r0 + 64;
  const int g0 = (c0 ^ (r0 & 3)) * 8;
  const int g1 = (c0 ^ (r1 & 3)) * 8;
  const size_t oA0 = (size_t)(bm + r0) * K + g0;
  const size_t oA1 = (size_t)(bm + r1) * K + g1;
  const size_t oB0 = (size_t)(bn + r0) * K + g0;
  const size_t oB1 = (size_t)(bn + r1) * K + g1;
  const int s0 = tid * 8, s1 = (tid + 256) * 8;

  int offA[4], offB[4];
  #pragma unroll
  for (int i = 0; i < 4; ++i) {
    int ra = wm + i * 16 + m16;
    offA[i] = ra * 32 + (quad ^ (ra & 3)) * 8;
    int rb = wn + i * 16 + m16;
    offB[i] = rb * 32 + (quad ^ (rb & 3)) * 8;
  }

  for (int k0 = 0; k0 < K; k0 += 32) {
    gld16(&lAh[s0], Ahi + oA0 + k0);
    gld16(&lAh[s1], Ahi + oA1 + k0);
    gld16(&lAl[s0], Alo + oA0 + k0);
    gld16(&lAl[s1], Alo + oA1 + k0);
    gld16(&lBh[s0], Whi + oB0 + k0);
    gld16(&lBh[s1], Whi + oB1 + k0);
    gld16(&lBl[s0], Wlo + oB0 + k0);
    gld16(&lBl[s1], Wlo + oB1 + k0);
    __syncthreads();
    bf16x8 afh[4], bfh[4];
    #pragma unroll
    for (int i = 0; i < 4; ++i) {
      afh[i] = *(const bf16x8*)&lAh[offA[i]];
      bfh[i] = *(const bf16x8*)&lBh[offB[i]];
    }
    #pragma unroll
    for (int mi = 0; mi < 4; ++mi)
      #pragma unroll
      for (int ni = 0; ni < 4; ++ni)
        acc[mi][ni] = __builtin_amdgcn_mfma_f32_16x16x32_bf16(afh[mi], bfh[ni], acc[mi][ni], 0, 0, 0);
    {
      bf16x8 bfl[4];
      #pragma unroll
      for (int i = 0; i < 4; ++i) bfl[i] = *(const bf16x8*)&lBl[offB[i]];
      #pragma unroll
      for (int mi = 0; mi < 4; ++mi)
        #pragma unroll
        for (int ni = 0; ni < 4; ++ni)
          acc[mi][ni] = __builtin_amdgcn_mfma_f32_16x16x32_bf16(afh[mi], bfl[ni], acc[mi][ni], 0, 0, 0);
    }
    {
      bf16x8 afl[4];
      #pragma unroll
      for (int i = 0; i < 4; ++i) afl[i] = *(const bf16x8*)&lAl[offA[i]];
      #pragma unroll
      for (int mi = 0; mi < 4; ++mi)
        #pragma unroll
        for (int ni = 0; ni < 4; ++ni)
          acc[mi][ni] = __builtin_amdgcn_mfma_f32_16x16x32_bf16(afl[mi], bfh[ni], acc[mi][ni], 0, 0, 0);
    }
    __syncthreads();
  }

  #pragma unroll
  for (int mi = 0; mi < 4; ++mi) {
    #pragma unroll
    for (int r = 0; r < 4; ++r) {
      size_t row = (size_t)(bm + wm + mi * 16 + quad * 4 + r);
      #pragma unroll
      for (int ni = 0; ni < 4; ++ni)
        C[row * N + bn + wn + ni * 16 + m16] = acc[mi][ni][r];
    }
  }
}

// bb/aa projections fused with beta / g=log(alpha). Reads fp32 hs (exact).
__global__ __launch_bounds__(128) void proj_ba_kernel(
    const float* __restrict__ hs, const float* __restrict__ b_w, const float* __restrict__ a_w,
    const float* __restrict__ dt_bias, const float* __restrict__ A_log,
    float* __restrict__ gout, float* __restrict__ beta) {
  const int bt = blockIdx.x;
  const int b = bt >> 10;
  const int t = bt & 1023;
  const int tid = threadIdx.x;
  const int grp = tid >> 3;
  const int l8 = tid & 7;
  const int h = grp & 7;
  const bool isA = grp >= 8;
  const float* w = (isA ? a_w : b_w) + (size_t)h * HID_;
  const float* x = hs + (size_t)bt * HID_;
  float s = 0.f;
  for (int e = l8*4; e < HID_; e += 32){
    float4 xv = *(const float4*)(x + e);
    float4 wv = *(const float4*)(w + e);
    s = fmaf(xv.x, wv.x, s);
    s = fmaf(xv.y, wv.y, s);
    s = fmaf(xv.z, wv.z, s);
    s = fmaf(xv.w, wv.w, s);
  }
  s += __shfl_xor(s,1); s += __shfl_xor(s,2); s += __shfl_xor(s,4);
  if (l8 == 0) {
    size_t o = ((size_t)(b*H_ + h))*T_ + t;
    if (!isA) {
      beta[o] = 1.f/(1.f+expf(-s));
    } else {
      float xx = s + dt_bias[h];
      float sp = fmaxf(xx,0.f) + log1pf(expf(-fabsf(xx)));   // softplus
      gout[o] = -expf(A_log[h]) * sp;                        // g = log(alpha)
    }
  }
}

// causal depthwise conv (K=4), 4 t-steps per thread (7 loads -> 4 outputs)
__global__ __launch_bounds__(256) void conv_route_kernel(
    const float* __restrict__ mixed, const float* __restrict__ conv_w,
    float* __restrict__ qb, float* __restrict__ kb, float* __restrict__ vb) {
  const int idx = blockIdx.x*256 + threadIdx.x;
  const int c = idx % CONV_DIM_;
  const int bt4 = idx / CONV_DIM_;
  const int b = bt4 >> 8;            // T/4 = 256 groups
  const int t0 = (bt4 & 255) * 4;
  float w0=conv_w[c*4],w1=conv_w[c*4+1],w2=conv_w[c*4+2],w3=conv_w[c*4+3];
  float x[7];
  #pragma unroll
  for (int j=0;j<7;++j){
    int tt = t0 - 3 + j;
    x[j] = (tt >= 0) ? mixed[((size_t)(b*T_+tt))*CONV_DIM_ + c] : 0.f;
  }
  const int part = c >> 10;
  const int cc = c & 1023;
  const int hh = cc >> 7;
  const int d = cc & 127;
  float* dst = part==0 ? qb : (part==1 ? kb : vb);
  size_t base = (((size_t)(b*H_+hh))*T_ + t0)*128 + d;
  #pragma unroll
  for (int i=0;i<4;++i){
    float s = fmaf(w0,x[i],fmaf(w1,x[i+1],fmaf(w2,x[i+2],w3*x[i+3])));
    dst[base + (size_t)i*128] = s;
  }
}

// Parallel precompute: 512 blocks = (bh, chunk).
// T = (I+A)^-1 (unit lower), B = incl-lower decayed QK^T.
__global__ __launch_bounds__(256) void scan_ab_kernel(
    const float* __restrict__ qb, const float* __restrict__ kb,
    const float* __restrict__ gbuf, const float* __restrict__ bbuf,
    float* __restrict__ Tg, float* __restrict__ Bg) {
  const int blk = blockIdx.x;
  const int bh = blk >> 4;
  const int ch = blk & 15;
  const int t0 = ch * 64;
  const int tid = threadIdx.x;
  __shared__ float sK[64][132];
  __shared__ float sAA[64][68];
  __shared__ float lL[64];
  __shared__ float bL[64];
  const float* kg = kb + (size_t)bh*T_*128;
  const float* qg = qb + (size_t)bh*T_*128;
  float* To = Tg + (size_t)blk*4096;
  float* Bo = Bg + (size_t)blk*4096;

  #pragma unroll
  for (int i = 0; i < 8; ++i) {
    int f4 = tid + 256*i;
    int row = f4 >> 5, c = f4 & 31;
    *(float4*)&sK[row][c*4] = *(const float4*)(kg + (size_t)(t0+row)*128 + c*4);
  }
  if (tid < 64) {
    float x = gbuf[(size_t)bh*T_ + t0 + tid];
    #pragma unroll
    for (int o = 1; o < 64; o <<= 1) {
      float y = __shfl_up(x, o);
      if (tid >= o) x += y;
    }
    lL[tid] = x;
    bL[tid] = bbuf[(size_t)bh*T_ + t0 + tid];
  }
  __syncthreads();

  const int it = tid >> 4, jt = tid & 15;
  {
    float acc[4][4] = {};
    if (jt <= it) {
      for (int kk = 0; kk < 128; kk += 4) {
        float4 ka[4], kc[4];
        #pragma unroll
        for (int r = 0; r < 4; ++r) {
          ka[r] = *(const float4*)&sK[it*4+r][kk];
          kc[r] = *(const float4*)&sK[jt*4+r][kk];
        }
        #pragma unroll
        for (int a = 0; a < 4; ++a)
          #pragma unroll
          for (int b = 0; b < 4; ++b) {
            acc[a][b] = fmaf(ka[a].x, kc[b].x, acc[a][b]);
            acc[a][b] = fmaf(ka[a].y, kc[b].y, acc[a][b]);
            acc[a][b] = fmaf(ka[a].z, kc[b].z, acc[a][b]);
            acc[a][b] = fmaf(ka[a].w, kc[b].w, acc[a][b]);
          }
      }
    }
    #pragma unroll
    for (int a = 0; a < 4; ++a) {
      int i = it*4 + a;
      float bi = bL[i], li = lL[i];
      #pragma unroll
      for (int b = 0; b < 4; ++b) {
        int j = jt*4 + b;
        sAA[i][j] = (j < i) ? bi * __expf(li - lL[j]) * acc[a][b] : 0.f;
      }
    }
  }
  {
    float acc[4][4] = {};
    if (jt <= it) {
      for (int kk = 0; kk < 128; kk += 4) {
        float4 qa[4], kc[4];
        #pragma unroll
        for (int r = 0; r < 4; ++r) {
          qa[r] = *(const float4*)(qg + (size_t)(t0+it*4+r)*128 + kk);
          kc[r] = *(const float4*)&sK[jt*4+r][kk];
        }
        #pragma unroll
        for (int a = 0; a < 4; ++a)
          #pragma unroll
          for (int b = 0; b < 4; ++b) {
            acc[a][b] = fmaf(qa[a].x, kc[b].x, acc[a][b]);
            acc[a][b] = fmaf(qa[a].y, kc[b].y, acc[a][b]);
            acc[a][b] = fmaf(qa[a].z, kc[b].z, acc[a][b]);
            acc[a][b] = fmaf(qa[a].w, kc[b].w, acc[a][b]);
          }
      }
    }
    #pragma unroll
    for (int a = 0; a < 4; ++a) {
      int i = it*4 + a;
      float li = lL[i];
      #pragma unroll
      for (int b = 0; b < 4; ++b) {
        int j = jt*4 + b;
        Bo[i*64 + j] = (j <= i) ? __expf(li - lL[j]) * acc[a][b] : 0.f;
      }
    }
  }
  __syncthreads();

  // invert (I+A): 4 waves x 16 cols, rows rr+4m per thread; wave-local chain
  {
    const int w = tid >> 6;
    const int ln = tid & 63;
    const int colc = w*16 + (ln & 15);
    const int rr = ln >> 4;
    float rh[16];
    #pragma unroll
    for (int m=0;m<16;++m) rh[m] = (rr + 4*m == colc) ? 1.f : 0.f;
    for (int j = 0; j < 63; ++j) {
      int src = ((j & 3) << 4) | (ln & 15);
      float wj = __shfl(rh[j >> 2], src);
      #pragma unroll
      for (int m=0;m<16;++m)
        rh[m] = fmaf(-sAA[rr + 4*m][j], wj, rh[m]);
    }
    #pragma unroll
    for (int m=0;m<16;++m)
      To[(rr + 4*m)*64 + colc] = rh[m];
  }
}

// Sequential chunked scan, 512 threads (8 waves), UT-transform form.
// 256 blocks = 32 bh x 8 dv-slices(16).
__global__ __launch_bounds__(512) void scan_seq_kernel(
    const float* __restrict__ qb, const float* __restrict__ kb, const float* __restrict__ vb,
    const float* __restrict__ gbuf, const float* __restrict__ bbuf,
    const float* __restrict__ Tg, const float* __restrict__ Bg,
    float* __restrict__ ob) {
  const int bh = blockIdx.x >> 3;
  const int sl = blockIdx.x & 7;
  const int tid = threadIdx.x;

  __shared__ float sK[64][132];
  __shared__ float sQ[64][132];
  __shared__ float sT[64][68];
  __shared__ float sBB[64][68];
  __shared__ float sS0T[16][132];
  __shared__ float sW[64][20];    // RHS
  __shared__ float sW2[64][20];   // W = T*RHS
  __shared__ float sW3T[16][68];  // W scaled, transposed [col][row] for U phase
  __shared__ float sQS[64][20];   // Q.S0
  __shared__ float lL[64];
  __shared__ float bL[64];

  const float* kg = kb + (size_t)bh*T_*128;
  const float* qg = qb + (size_t)bh*T_*128;
  const float* vg = vb + (size_t)bh*T_*128 + sl*16;
  const float* gg = gbuf + (size_t)bh*T_;
  const float* beg = bbuf + (size_t)bh*T_;
  float* og = ob + (size_t)bh*T_*128 + sl*16;

  const int ro  = tid >> 3;          // 0..63 row
  const int rem = tid & 7;
  const int kh  = rem >> 2;          // 0/1 half
  const int cg  = (rem & 3) * 4;     // col group (0,4,8,12)
  const int dcol = tid & 15, dk0 = (tid >> 4) * 4;   // S0-update decode

  for (int z = tid; z < 16*132; z += 512) ((float*)sS0T)[z] = 0.f;

  for (int ch = 0; ch < 16; ++ch) {
    const int t0 = ch * 64;
    const float* To = Tg + ((size_t)(bh*16 + ch))*4096;
    const float* Bo = Bg + ((size_t)(bh*16 + ch))*4096;
    __syncthreads();   // prev chunk's S0-update done; staging safe

    // ---- stage K, Q, T, B, cumsum
    #pragma unroll
    for (int i = 0; i < 4; ++i) {
      int f4 = tid + 512*i;
      int row = f4 >> 5, c = (f4 & 31) * 4;
      *(float4*)&sK[row][c] = *(const float4*)(kg + (size_t)(t0+row)*128 + c);
      *(float4*)&sQ[row][c] = *(const float4*)(qg + (size_t)(t0+row)*128 + c);
    }
    #pragma unroll
    for (int i = 0; i < 2; ++i) {
      int f4 = tid + 512*i;
      int row = f4 >> 4, c = (f4 & 15) * 4;
      *(float4*)&sT[row][c]  = *(const float4*)(To + row*64 + c);
      *(float4*)&sBB[row][c] = *(const float4*)(Bo + row*64 + c);
    }
    if (tid < 64) {
      float x = gg[t0 + tid];
      #pragma unroll
      for (int o = 1; o < 64; o <<= 1) {
        float y = __shfl_up(x, o);
        if (tid >= o) x += y;
      }
      lL[tid] = x;
      bL[tid] = beg[t0 + tid];
    }
    __syncthreads();

    // ---- F: kv = K.S0, qs = Q.S0 (interleaved k-split: kh*4 + 8j — avoids
    // 64-col same-bank aliasing); RHS -> sW, qs -> sQS
    {
      float a0=0,a1=0,a2=0,a3=0,q0=0,q1=0,q2=0,q3=0;
      for (int kk = kh*4; kk < 128; kk += 8) {
        float4 s0 = *(const float4*)&sS0T[cg+0][kk];
        float4 s1 = *(const float4*)&sS0T[cg+1][kk];
        float4 s2 = *(const float4*)&sS0T[cg+2][kk];
        float4 s3 = *(const float4*)&sS0T[cg+3][kk];
        float4 kv = *(const float4*)&sK[ro][kk];
        float4 qv = *(const float4*)&sQ[ro][kk];
        a0 = fmaf(kv.x,s0.x,fmaf(kv.y,s0.y,fmaf(kv.z,s0.z,fmaf(kv.w,s0.w,a0))));
        a1 = fmaf(kv.x,s1.x,fmaf(kv.y,s1.y,fmaf(kv.z,s1.z,fmaf(kv.w,s1.w,a1))));
        a2 = fmaf(kv.x,s2.x,fmaf(kv.y,s2.y,fmaf(kv.z,s2.z,fmaf(kv.w,s2.w,a2))));
        a3 = fmaf(kv.x,s3.x,fmaf(kv.y,s3.y,fmaf(kv.z,s3.z,fmaf(kv.w,s3.w,a3))));
        q0 = fmaf(qv.x,s0.x,fmaf(qv.y,s0.y,fmaf(qv.z,s0.z,fmaf(qv.w,s0.w,q0))));
        q1 = fmaf(qv.x,s1.x,fmaf(qv.y,s1.y,fmaf(qv.z,s1.z,fmaf(qv.w,s1.w,q1))));
        q2 = fmaf(qv.x,s2.x,fmaf(qv.y,s2.y,fmaf(qv.z,s2.z,fmaf(qv.w,s2.w,q2))));
        q3 = fmaf(qv.x,s3.x,fmaf(qv.y,s3.y,fmaf(qv.z,s3.z,fmaf(qv.w,s3.w,q3))));
      }
      a0 += __shfl_xor(a0,4); a1 += __shfl_xor(a1,4);
      a2 += __shfl_xor(a2,4); a3 += __shfl_xor(a3,4);
      q0 += __shfl_xor(q0,4); q1 += __shfl_xor(q1,4);
      q2 += __shfl_xor(q2,4); q3 += __shfl_xor(q3,4);
      if (kh == 0) {
        float be = bL[ro], ga = __expf(lL[ro]);
        float cgf = be * ga;
        float4 vvv = *(const float4*)(vg + (size_t)(t0+ro)*128 + cg);
        float4 w;
        w.x = be*vvv.x - cgf*a0;
        w.y = be*vvv.y - cgf*a1;
        w.z = be*vvv.z - cgf*a2;
        w.w = be*vvv.w - cgf*a3;
        *(float4*)&sW[ro][cg] = w;
        float4 qs; qs.x=q0; qs.y=q1; qs.z=q2; qs.w=q3;
        *(float4*)&sQS[ro][cg] = qs;
      }
    }
    __syncthreads();

    // ---- W = T * RHS (j-half split); write sW2 (unscaled) and sW3T (scaled, transposed)
    {
      float w0=0,w1=0,w2=0,w3=0;
      const int jbeg = kh * 32;
      for (int j = jbeg; j < jbeg + 32; ++j) {
        float tv = sT[ro][j];
        float4 r = *(const float4*)&sW[j][cg];
        w0 = fmaf(tv, r.x, w0);
        w1 = fmaf(tv, r.y, w1);
        w2 = fmaf(tv, r.z, w2);
        w3 = fmaf(tv, r.w, w3);
      }
      w0 += __shfl_xor(w0,4); w1 += __shfl_xor(w1,4);
      w2 += __shfl_xor(w2,4); w3 += __shfl_xor(w3,4);
      if (kh == 0) {
        float4 w; w.x=w0; w.y=w1; w.z=w2; w.w=w3;
        *(float4*)&sW2[ro][cg] = w;
        float sc = __expf(lL[63] - lL[ro]);
        sW3T[cg+0][ro] = w0*sc;
        sW3T[cg+1][ro] = w1*sc;
        sW3T[cg+2][ro] = w2*sc;
        sW3T[cg+3][ro] = w3*sc;
      }
    }
    __syncthreads();

    // ---- O = gamma*QS + B.W2 -> global (no barrier needed before U)
    {
      float w0=0,w1=0,w2=0,w3=0;
      const int jbeg = kh * 32;
      for (int j = jbeg; j < jbeg + 32; ++j) {
        float bv = sBB[ro][j];
        float4 r = *(const float4*)&sW2[j][cg];
        w0 = fmaf(bv, r.x, w0);
        w1 = fmaf(bv, r.y, w1);
        w2 = fmaf(bv, r.z, w2);
        w3 = fmaf(bv, r.w, w3);
      }
      w0 += __shfl_xor(w0,4); w1 += __shfl_xor(w1,4);
      w2 += __shfl_xor(w2,4); w3 += __shfl_xor(w3,4);
      if (kh == 0) {
        float ga = __expf(lL[ro]);
        float4 qs = *(const float4*)&sQS[ro][cg];
        float4 o;
        o.x = fmaf(ga, qs.x, w0);
        o.y = fmaf(ga, qs.y, w1);
        o.z = fmaf(ga, qs.z, w2);
        o.w = fmaf(ga, qs.w, w3);
        *(float4*)(og + (size_t)(t0+ro)*128 + cg) = o;
      }
    }

    // ---- U: S0 = gC*S0 + K^T W3 (b128 reads of transposed W3)
    {
      float gC = __expf(lL[63]);
      float4 sa = *(const float4*)&sS0T[dcol][dk0];
      sa.x*=gC; sa.y*=gC; sa.z*=gC; sa.w*=gC;
      for (int j = 0; j < 64; j += 4) {
        float4 wv4 = *(const float4*)&sW3T[dcol][j];
        float4 k0v = *(const float4*)&sK[j+0][dk0];
        float4 k1v = *(const float4*)&sK[j+1][dk0];
        float4 k2v = *(const float4*)&sK[j+2][dk0];
        float4 k3v = *(const float4*)&sK[j+3][dk0];
        sa.x = fmaf(k0v.x, wv4.x, sa.x); sa.y = fmaf(k0v.y, wv4.x, sa.y);
        sa.z = fmaf(k0v.z, wv4.x, sa.z); sa.w = fmaf(k0v.w, wv4.x, sa.w);
        sa.x = fmaf(k1v.x, wv4.y, sa.x); sa.y = fmaf(k1v.y, wv4.y, sa.y);
        sa.z = fmaf(k1v.z, wv4.y, sa.z); sa.w = fmaf(k1v.w, wv4.y, sa.w);
        sa.x = fmaf(k2v.x, wv4.z, sa.x); sa.y = fmaf(k2v.y, wv4.z, sa.y);
        sa.z = fmaf(k2v.z, wv4.z, sa.z); sa.w = fmaf(k2v.w, wv4.z, sa.w);
        sa.x = fmaf(k3v.x, wv4.w, sa.x); sa.y = fmaf(k3v.y, wv4.w, sa.y);
        sa.z = fmaf(k3v.z, wv4.w, sa.z); sa.w = fmaf(k3v.w, wv4.w, sa.w);
      }
      *(float4*)&sS0T[dcol][dk0] = sa;
    }
  }
}

// rmsnorm(o)*norm_w*silu(z) -> bf16 og; z bf16
__global__ __launch_bounds__(64) void gnorm_kernel(
    const float* __restrict__ ob, const unsigned short* __restrict__ zbb,
    const float* __restrict__ norm_w, unsigned short* __restrict__ og) {
  const int idx = blockIdx.x;
  const int t = idx & 1023;
  const int bh = idx >> 10;
  const int b = bh >> 3;
  const int h = bh & 7;
  const int tid = threadIdx.x;
  const float* o = ob + ((size_t)bh*T_ + t)*128;
  float2 ov = *(const float2*)(o + tid*2);
  float ss = fmaf(ov.x, ov.x, ov.y*ov.y);
  #pragma unroll
  for (int m=1; m<64; m<<=1) ss += __shfl_xor(ss, m);
  float inv = rsqrtf(ss*(1.f/128.f) + 1e-6f);
  size_t zoff = ((size_t)(b*T_+t))*1024 + (size_t)h*128 + tid*2;
  ushort2 zv = *(const ushort2*)(zbb + zoff);
  float z0 = bfu2f(zv.x), z1 = bfu2f(zv.y);
  float n0 = norm_w[tid*2], n1 = norm_w[tid*2+1];
  float r0 = ov.x*inv*n0 * z0/(1.f+expf(-z0));
  float r1 = ov.y*inv*n1 * z1/(1.f+expf(-z1));
  ushort2 ot;
  ot.x = f2bf(r0); ot.y = f2bf(r1);
  *(ushort2*)(og + zoff) = ot;
}

extern "C" void kernel_launch(void* const* d_in, const int* in_sizes, int n_in,
                              void* d_out, int out_size, void* d_ws, size_t ws_size,
                              hipStream_t stream) {
  const float* hs     = (const float*)d_in[0];
  const float* qkv_w  = (const float*)d_in[1];
  const float* z_w    = (const float*)d_in[2];
  const float* b_w    = (const float*)d_in[3];
  const float* a_w    = (const float*)d_in[4];
  const float* conv_w = (const float*)d_in[5];
  const float* dt_bias= (const float*)d_in[6];
  const float* A_log  = (const float*)d_in[7];
  const float* norm_w = (const float*)d_in[8];
  const float* out_w  = (const float*)d_in[9];
  float* out = (float*)d_out;

  char* wsp = (char*)d_ws;
  size_t off = 0;
  auto give = [&](size_t bytes)->char*{
    char* p = wsp + off; off += (bytes + 255) & ~(size_t)255; return p;
  };
  float* mixed  = (float*)give((size_t)MROWS*CONV_DIM_*4);  // 48 MB fp32 qkv
  unsigned short* zbuf = (unsigned short*)give((size_t)MROWS*1024*2);  // 8 MB
  unsigned short* outw_bf = (unsigned short*)give((size_t)HID_*1024*2); // 2 MB
  float* qb    = (float*)give((size_t)32*T_*128*4);          // 16 MB
  float* kb    = (float*)give((size_t)32*T_*128*4);          // 16 MB
  float* vb    = (float*)give((size_t)32*T_*128*4);          // 16 MB
  float* gbuf  = (float*)give((size_t)32*T_*4);
  float* beta  = (float*)give((size_t)32*T_*4);
  // overlays within mixed (48 MB = 12M floats), all stream-ordered:
  unsigned short* hs_hi = (unsigned short*)kb;
  unsigned short* hs_lo = (unsigned short*)kb + (size_t)MROWS*HID_;
  unsigned short* wc_hi = (unsigned short*)vb;
  unsigned short* wc_lo = (unsigned short*)vb + (size_t)CONV_DIM_*HID_;
  unsigned short* wz_bf = (unsigned short*)qb;
  float* ob = mixed;                                              // [0,4M) floats
  unsigned short* og = (unsigned short*)(mixed + (size_t)4*1024*1024); // [4M,6M)
  float* Tg = mixed + (size_t)6*1024*1024;                        // [6M,8M) = 8 MB
  float* Bg = mixed + (size_t)8*1024*1024;                        // [8M,10M) = 8 MB

  f2bf_split_kernel<<<dim3(MROWS*HID_/1024), 256, 0, stream>>>(hs, hs_hi, hs_lo, MROWS*HID_);
  f2bf_split_kernel<<<dim3(CONV_DIM_*HID_/1024), 256, 0, stream>>>(qkv_w, wc_hi, wc_lo, CONV_DIM_*HID_);
  f2bf_kernel<<<dim3(1024*HID_/1024), 256, 0, stream>>>(z_w, wz_bf, 1024*HID_);
  f2bf_kernel<<<dim3(1024*HID_/1024), 256, 0, stream>>>(out_w, outw_bf, 1024*HID_);

  gemm_mfma_split_kernel<<<dim3(CONV_DIM_/128, MROWS/128), 256, 0, stream>>>(
      hs_hi, hs_lo, wc_hi, wc_lo, mixed, MROWS, CONV_DIM_, HID_);
  gemm_mfma_kernel<1><<<dim3(1024/128, MROWS/128), 256, 0, stream>>>(
      hs_hi, wz_bf, zbuf, MROWS, 1024, HID_);
  proj_ba_kernel<<<dim3(MROWS), dim3(128), 0, stream>>>(hs, b_w, a_w, dt_bias, A_log, gbuf, beta);
  conv_route_kernel<<<dim3((B_*256*CONV_DIM_)/256), dim3(256), 0, stream>>>(mixed, conv_w, qb, kb, vb);
  scan_ab_kernel<<<dim3(512), dim3(256), 0, stream>>>(qb, kb, gbuf, beta, Tg, Bg);
  scan_seq_kernel<<<dim3(256), dim3(512), 0, stream>>>(qb, kb, vb, gbuf, beta, Tg, Bg, ob);
  gnorm_kernel<<<dim3(32*T_), dim3(64), 0, stream>>>(ob, zbuf, norm_w, og);
  gemm_mfma_kernel<0><<<dim3(1024/128, MROWS/128), 256, 0, stream>>>(og, outw_bf, out, MROWS, 1024, HID_);
}